// Round 5
// baseline (1086.351 us; speedup 1.0000x reference)
//
#include <hip/hip_runtime.h>

#define E_TOTAL 600000
#define NN 50000

typedef _Float16 half8 __attribute__((ext_vector_type(8)));
typedef float float4v __attribute__((ext_vector_type(4)));
typedef float float2v __attribute__((ext_vector_type(2)));

__device__ __forceinline__ float gelu_tanh(float x) {
    // jax.nn.gelu default (approximate=True): 0.5x(1+tanh(0.7978845608(x+0.044715x^3)))
    float u = 0.7978845608028654f * (x + 0.044715f * x * x * x);
    float ex = __expf(2.0f * u);            // inf/0 saturate tanh to +/-1 cleanly
    float t = 1.0f - 2.0f / (ex + 1.0f);
    return 0.5f * x * (1.0f + t);
}

// Activation LDS layout with bank swizzle (verified: 0 bank conflicts in R3).
__device__ __forceinline__ int act_idx(int c, int row, int q) {
    int idx = ((c * 128 + row) << 3) + q;
    idx ^= ((row >> 3) & 3) << 4;
    idx ^= (c & 1) << 3;
    return idx;
}

// Pack W[K][128] f32 (row-major) into MFMA B-fragment order, f16.
__global__ __launch_bounds__(256) void pack_all(
    const float* __restrict__ mW1, const float* __restrict__ mW2, const float* __restrict__ mW3,
    const float* __restrict__ uW1, const float* __restrict__ uW2,
    _Float16* __restrict__ dst)
{
    int t = blockIdx.x * 256 + threadIdx.x;
    const float* src;
    int loc;
    if (t < 40960)        { src = mW1; loc = t; }
    else if (t < 57344)   { src = mW2; loc = t - 40960; }
    else if (t < 73728)   { src = mW3; loc = t - 57344; }
    else if (t < 106496)  { src = uW1; loc = t - 73728; }
    else if (t < 122880)  { src = uW2; loc = t - 106496; }
    else return;
    int i   = loc & 7;
    int col = (loc >> 3) & 127;
    int c   = loc >> 10;
    dst[t] = (_Float16)src[(8 * c + i) * 128 + col];
}

__device__ __forceinline__ half8 cvt8(float4v x0, float4v x1) {
    half8 a;
    a[0] = (_Float16)x0[0]; a[1] = (_Float16)x0[1]; a[2] = (_Float16)x0[2]; a[3] = (_Float16)x0[3];
    a[4] = (_Float16)x1[0]; a[5] = (_Float16)x1[1]; a[6] = (_Float16)x1[2]; a[7] = (_Float16)x1[3];
    return a;
}

// edge_index dtype probe: int64 data viewed as int32 has all-zero odd words.
__device__ __forceinline__ int detect_i64(const int* ei) {
    int allz = 1;
    #pragma unroll
    for (int j = 1; j < 64; j += 2) allz &= (ei[j] == 0);
    return allz;
}

// ---------------- CSR build ----------------
__global__ __launch_bounds__(256) void count_kernel(const int* __restrict__ ei, int* __restrict__ cnt_i) {
    __shared__ int s_mode;
    if (threadIdx.x == 0) s_mode = detect_i64(ei);
    __syncthreads();
    int e = blockIdx.x * 256 + threadIdx.x;
    if (e >= E_TOTAL) return;
    int d = s_mode ? (int)((const long long*)ei)[E_TOTAL + e] : ei[E_TOTAL + e];
    atomicAdd(&cnt_i[d], 1);
}

__global__ __launch_bounds__(1024) void scan_kernel(const int* __restrict__ cnt_i, int* __restrict__ offs) {
    __shared__ int part[1024];
    const int t = threadIdx.x;
    const int PER = (NN + 1023) / 1024;   // 49
    const int base = t * PER;
    int s = 0;
    for (int j = 0; j < PER; ++j) { int idx = base + j; if (idx < NN) s += cnt_i[idx]; }
    part[t] = s;
    __syncthreads();
    for (int off = 1; off < 1024; off <<= 1) {   // Hillis-Steele inclusive scan
        int v = (t >= off) ? part[t - off] : 0;
        __syncthreads();
        part[t] += v;
        __syncthreads();
    }
    int run = (t == 0) ? 0 : part[t - 1];
    for (int j = 0; j < PER; ++j) { int idx = base + j; if (idx < NN) { offs[idx] = run; run += cnt_i[idx]; } }
    if (t == 1023) offs[NN] = part[1023];
}

__global__ __launch_bounds__(256) void fill_kernel(const int* __restrict__ ei, const int* __restrict__ offs,
                                                   int* __restrict__ cursor, int* __restrict__ perm) {
    __shared__ int s_mode;
    if (threadIdx.x == 0) s_mode = detect_i64(ei);
    __syncthreads();
    int e = blockIdx.x * 256 + threadIdx.x;
    if (e >= E_TOTAL) return;
    int d = s_mode ? (int)((const long long*)ei)[E_TOTAL + e] : ei[E_TOTAL + e];
    int pos = offs[d] + atomicAdd(&cursor[d], 1);
    perm[pos] = e;
}

// ---------------- gather-sum aggregation (one wave per node) ----------------
__global__ __launch_bounds__(256) void agg_kernel(const float* __restrict__ msgs,
                                                  const int* __restrict__ offs, const int* __restrict__ perm,
                                                  float* __restrict__ agg, float* __restrict__ cntf) {
    const int node = blockIdx.x * 4 + (threadIdx.x >> 6);
    const int l = threadIdx.x & 63;
    if (node >= NN) return;
    const int beg = offs[node], end = offs[node + 1];
    float2v s = {0.0f, 0.0f};
    const float2v* base = (const float2v*)msgs;
    for (int j = beg; j < end; ++j) {
        const int e = perm[j];
        float2v v = __builtin_nontemporal_load(&base[(size_t)e * 64 + l]);
        s.x += v.x; s.y += v.y;
    }
    ((float2v*)agg)[(size_t)node * 64 + l] = s;
    if (l == 0) cntf[node] = (float)(end - beg);
}

// ---------------- Message MLP ----------------
// 256 threads = 4 waves; 128 edges per block; wave w owns edge-rows [32w, 32w+32).
// ATOMIC=1: legacy f32-atomic scatter into agg + cnt (fallback if ws too small).
// ATOMIC=0: dense row-major store to msgs[E][128] f32 (no RMW, no atomics),
//           non-temporal (307 MB one-shot stream; keep L2 for h + weights).
template<int ATOMIC>
__global__ __launch_bounds__(256) void msg_kernel(
    const float* __restrict__ h, const int* __restrict__ ei, const float* __restrict__ eattr,
    const _Float16* __restrict__ pw1, const _Float16* __restrict__ pw2, const _Float16* __restrict__ pw3,
    const float* __restrict__ mb1, const float* __restrict__ mb2, const float* __restrict__ mb3,
    float* __restrict__ msgs, float* __restrict__ agg, float* __restrict__ cnt)
{
    __shared__ int s_src[128];
    __shared__ int s_dst[128];
    __shared__ int s_mode;
    __shared__ __align__(16) _Float16 s_act[16 * 128 * 8];

    const int tid = threadIdx.x;
    const int e0  = blockIdx.x * 128;

    if (tid == 0) s_mode = detect_i64(ei);
    __syncthreads();

    if (tid < 128) {
        int e  = e0 + tid;
        int ec = e < E_TOTAL ? e : E_TOTAL - 1;
        int srcn, dstn;
        if (s_mode) {
            const long long* e64 = (const long long*)ei;
            srcn = (int)e64[ec];
            dstn = (int)e64[E_TOTAL + ec];
        } else {
            srcn = ei[ec];
            dstn = ei[E_TOTAL + ec];
        }
        s_src[tid] = srcn;
        s_dst[tid] = dstn;
        if (ATOMIC && e < E_TOTAL) unsafeAtomicAdd(&cnt[dstn], 1.0f);
    }
    __syncthreads();

    const int w = tid >> 6, l = tid & 63, lhi = l >> 4, llo = l & 15;
    const int r0 = 32 * w;
    const float4v fzero = {0.0f, 0.0f, 0.0f, 0.0f};

    size_t srcOff[2], dstOff[2], eOff[2];
    #pragma unroll
    for (int ms = 0; ms < 2; ++ms) {
        const int row = r0 + 16 * ms + llo;
        srcOff[ms] = (size_t)s_src[row] * 128;
        dstOff[ms] = (size_t)s_dst[row] * 128;
        int e = e0 + row; if (e >= E_TOTAL) e = E_TOTAL - 1;
        eOff[ms] = (size_t)e * 64;
    }

    // ---- GEMM1: X[128][320] @ W1[320][128] ----
    float4v acc[2][8];
    #pragma unroll
    for (int ms = 0; ms < 2; ++ms)
        #pragma unroll
        for (int t = 0; t < 8; ++t) acc[ms][t] = fzero;

    #pragma unroll
    for (int s = 0; s < 10; ++s) {
        const int kbase = 32 * s + 8 * lhi;
        half8 af[2];
        #pragma unroll
        for (int ms = 0; ms < 2; ++ms) {
            const float* p;
            if (kbase < 128)      p = h + srcOff[ms] + kbase;
            else if (kbase < 256) p = h + dstOff[ms] + (kbase - 128);
            else                  p = eattr + eOff[ms] + (kbase - 256);
            float4v x0 = *(const float4v*)p;
            float4v x1 = *(const float4v*)(p + 4);
            af[ms] = cvt8(x0, x1);
        }
        const int bbase = ((4 * s + lhi) * 128 + llo) << 3;
        #pragma unroll
        for (int t = 0; t < 8; ++t) {
            const half8 b = *(const half8*)(pw1 + bbase + (t << 7));
            acc[0][t] = __builtin_amdgcn_mfma_f32_16x16x32_f16(af[0], b, acc[0][t], 0, 0, 0);
            acc[1][t] = __builtin_amdgcn_mfma_f32_16x16x32_f16(af[1], b, acc[1][t], 0, 0, 0);
        }
    }

    #pragma unroll
    for (int t = 0; t < 8; ++t) {
        const int col = 16 * t + llo;
        const float b1 = mb1[col];
        #pragma unroll
        for (int ms = 0; ms < 2; ++ms)
            #pragma unroll
            for (int i = 0; i < 4; ++i) {
                const int row = r0 + 16 * ms + 4 * lhi + i;
                float v = gelu_tanh(acc[ms][t][i] + b1);
                s_act[act_idx(col >> 3, row, col & 7)] = (_Float16)v;
            }
    }

    // ---- GEMM2 ----
    float4v acc2[2][8];
    #pragma unroll
    for (int ms = 0; ms < 2; ++ms)
        #pragma unroll
        for (int t = 0; t < 8; ++t) acc2[ms][t] = fzero;

    #pragma unroll
    for (int s = 0; s < 4; ++s) {
        half8 af[2];
        #pragma unroll
        for (int ms = 0; ms < 2; ++ms) {
            const int row = r0 + 16 * ms + llo;
            af[ms] = *(const half8*)&s_act[act_idx(4 * s + lhi, row, 0)];
        }
        const int bbase = ((4 * s + lhi) * 128 + llo) << 3;
        #pragma unroll
        for (int t = 0; t < 8; ++t) {
            const half8 b = *(const half8*)(pw2 + bbase + (t << 7));
            acc2[0][t] = __builtin_amdgcn_mfma_f32_16x16x32_f16(af[0], b, acc2[0][t], 0, 0, 0);
            acc2[1][t] = __builtin_amdgcn_mfma_f32_16x16x32_f16(af[1], b, acc2[1][t], 0, 0, 0);
        }
    }

    #pragma unroll
    for (int t = 0; t < 8; ++t) {
        const int col = 16 * t + llo;
        const float b2 = mb2[col];
        #pragma unroll
        for (int ms = 0; ms < 2; ++ms)
            #pragma unroll
            for (int i = 0; i < 4; ++i) {
                const int row = r0 + 16 * ms + 4 * lhi + i;
                float v = gelu_tanh(acc2[ms][t][i] + b2);
                s_act[act_idx(col >> 3, row, col & 7)] = (_Float16)v;
            }
    }

    // ---- GEMM3 ----
    float4v acc3[2][8];
    #pragma unroll
    for (int ms = 0; ms < 2; ++ms)
        #pragma unroll
        for (int t = 0; t < 8; ++t) acc3[ms][t] = fzero;

    #pragma unroll
    for (int s = 0; s < 4; ++s) {
        half8 af[2];
        #pragma unroll
        for (int ms = 0; ms < 2; ++ms) {
            const int row = r0 + 16 * ms + llo;
            af[ms] = *(const half8*)&s_act[act_idx(4 * s + lhi, row, 0)];
        }
        const int bbase = ((4 * s + lhi) * 128 + llo) << 3;
        #pragma unroll
        for (int t = 0; t < 8; ++t) {
            const half8 b = *(const half8*)(pw3 + bbase + (t << 7));
            acc3[0][t] = __builtin_amdgcn_mfma_f32_16x16x32_f16(af[0], b, acc3[0][t], 0, 0, 0);
            acc3[1][t] = __builtin_amdgcn_mfma_f32_16x16x32_f16(af[1], b, acc3[1][t], 0, 0, 0);
        }
    }

    float mb3v[8];
    #pragma unroll
    for (int t = 0; t < 8; ++t) mb3v[t] = mb3[16 * t + llo];

    #pragma unroll
    for (int ms = 0; ms < 2; ++ms)
        #pragma unroll
        for (int i = 0; i < 4; ++i) {
            const int row = r0 + 16 * ms + 4 * lhi + i;
            if (e0 + row < E_TOTAL) {
                if (ATOMIC) {
                    const size_t dbase = (size_t)s_dst[row] * 128;
                    #pragma unroll
                    for (int t = 0; t < 8; ++t)
                        unsafeAtomicAdd(&agg[dbase + 16 * t + llo], acc3[ms][t][i] + mb3v[t]);
                } else {
                    float* mrow = msgs + (size_t)(e0 + row) * 128;
                    #pragma unroll
                    for (int t = 0; t < 8; ++t)
                        __builtin_nontemporal_store(acc3[ms][t][i] + mb3v[t], &mrow[16 * t + llo]);
                }
            }
        }
}

// ---------------- Update MLP + residual + LayerNorm ----------------
__global__ __launch_bounds__(256) void upd_kernel(
    const float* __restrict__ h,
    const _Float16* __restrict__ pu1, const _Float16* __restrict__ pu2,
    const float* __restrict__ ub1, const float* __restrict__ ub2,
    const float* __restrict__ gamma, const float* __restrict__ beta,
    const float* __restrict__ agg, const float* __restrict__ cnt,
    float* __restrict__ out)
{
    __shared__ __align__(16) _Float16 s_act[16 * 128 * 8];

    const int tid = threadIdx.x;
    const int n0  = blockIdx.x * 128;
    const int w = tid >> 6, l = tid & 63, lhi = l >> 4, llo = l & 15;
    const int r0 = 32 * w;
    const float4v fzero = {0.0f, 0.0f, 0.0f, 0.0f};

    float rcp[2];
    size_t nodeOff[2];
    #pragma unroll
    for (int ms = 0; ms < 2; ++ms) {
        int node = n0 + r0 + 16 * ms + llo;
        if (node >= NN) node = NN - 1;
        nodeOff[ms] = (size_t)node * 128;
        rcp[ms] = 1.0f / (cnt[node] + 1e-8f);
    }

    float4v acc[2][8];
    #pragma unroll
    for (int ms = 0; ms < 2; ++ms)
        #pragma unroll
        for (int t = 0; t < 8; ++t) acc[ms][t] = fzero;

    #pragma unroll
    for (int s = 0; s < 8; ++s) {
        const int kbase = 32 * s + 8 * lhi;
        half8 af[2];
        #pragma unroll
        for (int ms = 0; ms < 2; ++ms) {
            const float* p;
            float sc;
            if (kbase < 128) { p = h + nodeOff[ms] + kbase; sc = 1.0f; }
            else             { p = agg + nodeOff[ms] + (kbase - 128); sc = rcp[ms]; }
            float4v x0 = *(const float4v*)p;
            float4v x1 = *(const float4v*)(p + 4);
            x0 *= sc; x1 *= sc;
            af[ms] = cvt8(x0, x1);
        }
        const int bbase = ((4 * s + lhi) * 128 + llo) << 3;
        #pragma unroll
        for (int t = 0; t < 8; ++t) {
            const half8 b = *(const half8*)(pu1 + bbase + (t << 7));
            acc[0][t] = __builtin_amdgcn_mfma_f32_16x16x32_f16(af[0], b, acc[0][t], 0, 0, 0);
            acc[1][t] = __builtin_amdgcn_mfma_f32_16x16x32_f16(af[1], b, acc[1][t], 0, 0, 0);
        }
    }

    #pragma unroll
    for (int t = 0; t < 8; ++t) {
        const int col = 16 * t + llo;
        const float b1 = ub1[col];
        #pragma unroll
        for (int ms = 0; ms < 2; ++ms)
            #pragma unroll
            for (int i = 0; i < 4; ++i) {
                const int row = r0 + 16 * ms + 4 * lhi + i;
                float v = gelu_tanh(acc[ms][t][i] + b1);
                s_act[act_idx(col >> 3, row, col & 7)] = (_Float16)v;
            }
    }

    float4v acc2[2][8];
    #pragma unroll
    for (int ms = 0; ms < 2; ++ms)
        #pragma unroll
        for (int t = 0; t < 8; ++t) acc2[ms][t] = fzero;

    #pragma unroll
    for (int s = 0; s < 4; ++s) {
        half8 af[2];
        #pragma unroll
        for (int ms = 0; ms < 2; ++ms) {
            const int row = r0 + 16 * ms + llo;
            af[ms] = *(const half8*)&s_act[act_idx(4 * s + lhi, row, 0)];
        }
        const int bbase = ((4 * s + lhi) * 128 + llo) << 3;
        #pragma unroll
        for (int t = 0; t < 8; ++t) {
            const half8 b = *(const half8*)(pu2 + bbase + (t << 7));
            acc2[0][t] = __builtin_amdgcn_mfma_f32_16x16x32_f16(af[0], b, acc2[0][t], 0, 0, 0);
            acc2[1][t] = __builtin_amdgcn_mfma_f32_16x16x32_f16(af[1], b, acc2[1][t], 0, 0, 0);
        }
    }

    float ub2v[8], gv[8], bv[8];
    #pragma unroll
    for (int t = 0; t < 8; ++t) {
        const int col = 16 * t + llo;
        ub2v[t] = ub2[col]; gv[t] = gamma[col]; bv[t] = beta[col];
    }

    #pragma unroll
    for (int ms = 0; ms < 2; ++ms)
        #pragma unroll
        for (int i = 0; i < 4; ++i) {
            const int noderow = n0 + r0 + 16 * ms + 4 * lhi + i;
            const int nodec = noderow < NN ? noderow : NN - 1;
            float y[8];
            float sum = 0.0f;
            #pragma unroll
            for (int t = 0; t < 8; ++t) {
                const int col = 16 * t + llo;
                float v = acc2[ms][t][i] + ub2v[t] + h[(size_t)nodec * 128 + col];
                y[t] = v; sum += v;
            }
            sum += __shfl_xor(sum, 1, 16);
            sum += __shfl_xor(sum, 2, 16);
            sum += __shfl_xor(sum, 4, 16);
            sum += __shfl_xor(sum, 8, 16);
            const float mu = sum * (1.0f / 128.0f);
            float sq = 0.0f;
            #pragma unroll
            for (int t = 0; t < 8; ++t) { float d = y[t] - mu; sq += d * d; }
            sq += __shfl_xor(sq, 1, 16);
            sq += __shfl_xor(sq, 2, 16);
            sq += __shfl_xor(sq, 4, 16);
            sq += __shfl_xor(sq, 8, 16);
            const float rs = rsqrtf(sq * (1.0f / 128.0f) + 1e-5f);
            if (noderow < NN) {
                #pragma unroll
                for (int t = 0; t < 8; ++t) {
                    const int col = 16 * t + llo;
                    out[(size_t)noderow * 128 + col] = (y[t] - mu) * rs * gv[t] + bv[t];
                }
            }
        }
}

extern "C" void kernel_launch(void* const* d_in, const int* in_sizes, int n_in,
                              void* d_out, int out_size, void* d_ws, size_t ws_size,
                              hipStream_t stream) {
    const float* h     = (const float*)d_in[0];
    const int*   ei    = (const int*)d_in[1];
    const float* eattr = (const float*)d_in[2];
    const float* mW1   = (const float*)d_in[3];
    const float* mb1   = (const float*)d_in[4];
    const float* mW2   = (const float*)d_in[5];
    const float* mb2   = (const float*)d_in[6];
    const float* mW3   = (const float*)d_in[7];
    const float* mb3   = (const float*)d_in[8];
    const float* uW1   = (const float*)d_in[9];
    const float* ub1   = (const float*)d_in[10];
    const float* uW2   = (const float*)d_in[11];
    const float* ub2   = (const float*)d_in[12];
    const float* gamma = (const float*)d_in[13];
    const float* beta  = (const float*)d_in[14];
    float* out = (float*)d_out;

    char* ws = (char*)d_ws;

    // Main (two-phase) layout
    const size_t OFF_MSGS   = 0;                       // 600000*128*4 = 307,200,000
    const size_t OFF_AGG    = 307200000;               // 25,600,000
    const size_t OFF_CNTI   = 332800000;               // 200,000
    const size_t OFF_CURSOR = 333000000;               // 200,000
    const size_t OFF_OFFS   = 333200000;               // 200,004
    const size_t OFF_PERM   = 333400064;               // 2,400,000
    const size_t OFF_CNTF   = 335800064;               // 200,000
    const size_t OFF_PW     = 336000064;               // 245,760
    const size_t NEED       = 336245824;

    if (ws_size >= NEED) {
        float* msgs   = (float*)(ws + OFF_MSGS);
        float* agg    = (float*)(ws + OFF_AGG);
        int*   cnt_i  = (int*)(ws + OFF_CNTI);
        int*   cursor = (int*)(ws + OFF_CURSOR);
        int*   offs   = (int*)(ws + OFF_OFFS);
        int*   perm   = (int*)(ws + OFF_PERM);
        float* cntf   = (float*)(ws + OFF_CNTF);
        _Float16* pw  = (_Float16*)(ws + OFF_PW);
        _Float16* pw1 = pw;
        _Float16* pw2 = pw + 40960;
        _Float16* pw3 = pw + 57344;
        _Float16* pu1 = pw + 73728;
        _Float16* pu2 = pw + 106496;

        hipMemsetAsync(ws + OFF_CNTI, 0, 400000, stream);   // cnt_i + cursor

        pack_all<<<480, 256, 0, stream>>>(mW1, mW2, mW3, uW1, uW2, pw);
        count_kernel<<<(E_TOTAL + 255) / 256, 256, 0, stream>>>(ei, cnt_i);
        scan_kernel<<<1, 1024, 0, stream>>>(cnt_i, offs);
        fill_kernel<<<(E_TOTAL + 255) / 256, 256, 0, stream>>>(ei, offs, cursor, perm);

        msg_kernel<0><<<(E_TOTAL + 127) / 128, 256, 0, stream>>>(
            h, ei, eattr, pw1, pw2, pw3, mb1, mb2, mb3, msgs, nullptr, nullptr);

        agg_kernel<<<NN / 4, 256, 0, stream>>>(msgs, offs, perm, agg, cntf);

        upd_kernel<<<(NN + 127) / 128, 256, 0, stream>>>(
            h, pu1, pu2, ub1, ub2, gamma, beta, agg, cntf, out);
    } else {
        // Fallback: legacy atomic-scatter path (fits in ~26 MB)
        float* agg = (float*)ws;                        // 25,600,000
        float* cnt = (float*)(ws + 25600000);           // 200,000
        _Float16* pw  = (_Float16*)(ws + 25800000);
        _Float16* pw1 = pw;
        _Float16* pw2 = pw + 40960;
        _Float16* pw3 = pw + 57344;
        _Float16* pu1 = pw + 73728;
        _Float16* pu2 = pw + 106496;

        hipMemsetAsync(ws, 0, 25800000, stream);

        pack_all<<<480, 256, 0, stream>>>(mW1, mW2, mW3, uW1, uW2, pw);

        msg_kernel<1><<<(E_TOTAL + 127) / 128, 256, 0, stream>>>(
            h, ei, eattr, pw1, pw2, pw3, mb1, mb2, mb3, nullptr, agg, cnt);

        upd_kernel<<<(NN + 127) / 128, 256, 0, stream>>>(
            h, pu1, pu2, ub1, ub2, gamma, beta, agg, cnt, out);
    }
}

// Round 7
// 858.234 us; speedup vs baseline: 1.2658x; 1.2658x over previous
//
#include <hip/hip_runtime.h>

#define E_TOTAL 600000
#define NN 50000

typedef _Float16 half8 __attribute__((ext_vector_type(8)));
typedef _Float16 half2v __attribute__((ext_vector_type(2)));
typedef float float4v __attribute__((ext_vector_type(4)));
typedef float float2v __attribute__((ext_vector_type(2)));

__device__ __forceinline__ float gelu_tanh(float x) {
    // jax.nn.gelu approximate=True
    float u = 0.7978845608028654f * (x + 0.044715f * x * x * x);
    float ex = __expf(2.0f * u);
    float t = 1.0f - 2.0f / (ex + 1.0f);
    return 0.5f * x * (1.0f + t);
}

// 128-row activation LDS swizzle (upd kernel). Verified 0 conflicts in R3/R5.
__device__ __forceinline__ int act_idx(int c, int row, int q) {
    int idx = ((c * 128 + row) << 3) + q;
    idx ^= ((row >> 3) & 3) << 4;
    idx ^= (c & 1) << 3;
    return idx;
}
// 64-row variant (msg kernel, 2-wave blocks).
__device__ __forceinline__ int act_idx64(int c, int row, int q) {
    int idx = ((c * 64 + row) << 3) + q;
    idx ^= ((row >> 3) & 3) << 4;
    idx ^= (c & 1) << 3;
    return idx;
}

__device__ __forceinline__ half8 cvt8(float4v x0, float4v x1) {
    half8 a;
    a[0] = (_Float16)x0[0]; a[1] = (_Float16)x0[1]; a[2] = (_Float16)x0[2]; a[3] = (_Float16)x0[3];
    a[4] = (_Float16)x1[0]; a[5] = (_Float16)x1[1]; a[6] = (_Float16)x1[2]; a[7] = (_Float16)x1[3];
    return a;
}

// Pack W[K][128] f32 row-major into MFMA B-fragment order, f16.
__global__ __launch_bounds__(256) void pack_all(
    const float* __restrict__ mW1, const float* __restrict__ mW2, const float* __restrict__ mW3,
    const float* __restrict__ uW1, const float* __restrict__ uW2,
    _Float16* __restrict__ dst)
{
    int t = blockIdx.x * 256 + threadIdx.x;
    const float* src;
    int loc;
    if (t < 40960)        { src = mW1; loc = t; }
    else if (t < 57344)   { src = mW2; loc = t - 40960; }
    else if (t < 73728)   { src = mW3; loc = t - 57344; }
    else if (t < 106496)  { src = uW1; loc = t - 73728; }
    else if (t < 122880)  { src = uW2; loc = t - 106496; }
    else return;
    int i   = loc & 7;
    int col = (loc >> 3) & 127;
    int c   = loc >> 10;
    dst[t] = (_Float16)src[(8 * c + i) * 128 + col];
}

// Pre-convert h (6.4M f32) and eattr (38.4M f32) to f16, 8 elems/thread chunk.
__global__ __launch_bounds__(256) void cvt_pre(
    const float* __restrict__ h, const float* __restrict__ ea,
    _Float16* __restrict__ hf, _Float16* __restrict__ ef)
{
    const int stride = gridDim.x * 256;
    for (int i = blockIdx.x * 256 + threadIdx.x; i < 5600000; i += stride) {
        if (i < 800000) {
            float4v a = ((const float4v*)h)[2 * i];
            float4v b = ((const float4v*)h)[2 * i + 1];
            ((half8*)hf)[i] = cvt8(a, b);
        } else {
            int j = i - 800000;
            float4v a = ((const float4v*)ea)[2 * j];
            float4v b = ((const float4v*)ea)[2 * j + 1];
            ((half8*)ef)[j] = cvt8(a, b);
        }
    }
}

// edge_index dtype probe: int64 viewed as int32 has all-zero odd words.
__device__ __forceinline__ int detect_i64(const int* ei) {
    int allz = 1;
    #pragma unroll
    for (int j = 1; j < 64; j += 2) allz &= (ei[j] == 0);
    return allz;
}

// ---------------- CSR build ----------------
__global__ __launch_bounds__(256) void count_kernel(const int* __restrict__ ei, int* __restrict__ cnt_i) {
    __shared__ int s_mode;
    if (threadIdx.x == 0) s_mode = detect_i64(ei);
    __syncthreads();
    int e = blockIdx.x * 256 + threadIdx.x;
    if (e >= E_TOTAL) return;
    int d = s_mode ? (int)((const long long*)ei)[E_TOTAL + e] : ei[E_TOTAL + e];
    atomicAdd(&cnt_i[d], 1);
}

__global__ __launch_bounds__(1024) void scan_kernel(const int* __restrict__ cnt_i, int* __restrict__ offs) {
    __shared__ int part[1024];
    const int t = threadIdx.x;
    const int PER = (NN + 1023) / 1024;   // 49
    const int base = t * PER;
    int s = 0;
    for (int j = 0; j < PER; ++j) { int idx = base + j; if (idx < NN) s += cnt_i[idx]; }
    part[t] = s;
    __syncthreads();
    for (int off = 1; off < 1024; off <<= 1) {
        int v = (t >= off) ? part[t - off] : 0;
        __syncthreads();
        part[t] += v;
        __syncthreads();
    }
    int run = (t == 0) ? 0 : part[t - 1];
    for (int j = 0; j < PER; ++j) { int idx = base + j; if (idx < NN) { offs[idx] = run; run += cnt_i[idx]; } }
    if (t == 1023) offs[NN] = part[1023];
}

__global__ __launch_bounds__(256) void fill_kernel(const int* __restrict__ ei, const int* __restrict__ offs,
                                                   int* __restrict__ cursor, int* __restrict__ perm) {
    __shared__ int s_mode;
    if (threadIdx.x == 0) s_mode = detect_i64(ei);
    __syncthreads();
    int e = blockIdx.x * 256 + threadIdx.x;
    if (e >= E_TOTAL) return;
    int d = s_mode ? (int)((const long long*)ei)[E_TOTAL + e] : ei[E_TOTAL + e];
    int pos = offs[d] + atomicAdd(&cursor[d], 1);
    perm[pos] = e;
}

// ---------------- gather-sum aggregation (one wave per node, f16 msgs) ----------------
__global__ __launch_bounds__(256) void agg_kernel(const _Float16* __restrict__ msgs,
                                                  const int* __restrict__ offs, const int* __restrict__ perm,
                                                  float* __restrict__ agg, float* __restrict__ cntf) {
    const int node = blockIdx.x * 4 + (threadIdx.x >> 6);   // NN % 4 == 0, no guard
    const int l = threadIdx.x & 63;
    const int beg = offs[node], end = offs[node + 1];
    float2v s = {0.0f, 0.0f};
    const half2v* base = (const half2v*)msgs;
    for (int j = beg; j < end; ++j) {
        const int e = perm[j];
        half2v v = __builtin_nontemporal_load(&base[(size_t)e * 64 + l]);
        s.x += (float)v[0]; s.y += (float)v[1];
    }
    ((float2v*)agg)[(size_t)node * 64 + l] = s;
    if (l == 0) cntf[node] = (float)(end - beg);
}

// ---------------- Message MLP ----------------
// 128 threads = 2 waves; 64 edges/block (600000/64 = 9375 exact, no guards).
// Wave w owns edge-rows [32w, 32w+32). All A-operands f16 (hf16/ef16), loaded
// with a 4-deep prefetch rotation (8 gathers in flight/wave).
// ATOMIC=1: f32-atomic scatter fallback; ATOMIC=0: dense f16 NT store to msgs.
template<int ATOMIC>
__global__ __launch_bounds__(128, 3) void msg_kernel(
    const _Float16* __restrict__ hf16, const int* __restrict__ ei, const _Float16* __restrict__ ef16,
    const _Float16* __restrict__ pw1, const _Float16* __restrict__ pw2, const _Float16* __restrict__ pw3,
    const float* __restrict__ mb1, const float* __restrict__ mb2, const float* __restrict__ mb3,
    _Float16* __restrict__ msgs, float* __restrict__ agg, float* __restrict__ cnt)
{
    __shared__ int s_src[64];
    __shared__ int s_dst[64];
    __shared__ int s_mode;
    __shared__ __align__(16) _Float16 s_act[16 * 64 * 8];   // 16 KB

    const int tid = threadIdx.x;
    const int e0  = blockIdx.x * 64;

    if (tid == 0) s_mode = detect_i64(ei);
    __syncthreads();

    if (tid < 64) {
        int e = e0 + tid;
        int srcn, dstn;
        if (s_mode) {
            const long long* e64 = (const long long*)ei;
            srcn = (int)e64[e];
            dstn = (int)e64[E_TOTAL + e];
        } else {
            srcn = ei[e];
            dstn = ei[E_TOTAL + e];
        }
        s_src[tid] = srcn;
        s_dst[tid] = dstn;
        if (ATOMIC) unsafeAtomicAdd(&cnt[dstn], 1.0f);
    }
    __syncthreads();

    const int w = tid >> 6, l = tid & 63, lhi = l >> 4, llo = l & 15;
    const int r0 = 32 * w;
    const float4v fzero = {0.0f, 0.0f, 0.0f, 0.0f};

    // Per-lane A-row base pointers (rows r0+llo, r0+16+llo)
    const _Float16* srcP[2];
    const _Float16* dstP[2];
    const _Float16* eP[2];
    #pragma unroll
    for (int ms = 0; ms < 2; ++ms) {
        const int row = r0 + 16 * ms + llo;
        srcP[ms] = hf16 + (size_t)s_src[row] * 128 + 8 * lhi;
        dstP[ms] = hf16 + (size_t)s_dst[row] * 128 + 8 * lhi;
        eP[ms]   = ef16 + (size_t)(e0 + row) * 64 + 8 * lhi;
    }

    // ---- GEMM1: X[64][320] @ W1 (K-steps s=0..9), 4-deep A prefetch ----
    // K map: s=0..3 -> h[src] (k 0..127), s=4..7 -> h[dst] (k 128..255),
    //        s=8..9 -> eattr (k 256..319). Lane covers 8*lhi..8*lhi+7 within
    //        each 32-wide K-step.
    float4v acc[2][8];
    #pragma unroll
    for (int ms = 0; ms < 2; ++ms)
        #pragma unroll
        for (int t = 0; t < 8; ++t) acc[ms][t] = fzero;

    half8 af[4][2];
    #pragma unroll
    for (int s = 0; s < 4; ++s)
        #pragma unroll
        for (int ms = 0; ms < 2; ++ms)
            af[s][ms] = *(const half8*)(srcP[ms] + 32 * s);

    #pragma unroll
    for (int s = 0; s < 10; ++s) {
        const int bbase = ((4 * s + lhi) * 128 + llo) << 3;
        #pragma unroll
        for (int t = 0; t < 8; ++t) {
            const half8 b = *(const half8*)(pw1 + bbase + (t << 7));
            acc[0][t] = __builtin_amdgcn_mfma_f32_16x16x32_f16(af[s & 3][0], b, acc[0][t], 0, 0, 0);
            acc[1][t] = __builtin_amdgcn_mfma_f32_16x16x32_f16(af[s & 3][1], b, acc[1][t], 0, 0, 0);
        }
        if (s + 4 <= 9) {
            const int sn = s + 4;
            #pragma unroll
            for (int ms = 0; ms < 2; ++ms) {
                const _Float16* p;
                if (sn < 8) p = dstP[ms] + 32 * (sn - 4);
                else        p = eP[ms] + 32 * (sn - 8);
                af[sn & 3][ms] = *(const half8*)p;
            }
        }
    }

    // E1: bias + gelu -> s_act
    #pragma unroll
    for (int t = 0; t < 8; ++t) {
        const int col = 16 * t + llo;
        const float b1 = mb1[col];
        #pragma unroll
        for (int ms = 0; ms < 2; ++ms)
            #pragma unroll
            for (int i = 0; i < 4; ++i) {
                const int row = r0 + 16 * ms + 4 * lhi + i;
                float v = gelu_tanh(acc[ms][t][i] + b1);
                s_act[act_idx64(col >> 3, row, col & 7)] = (_Float16)v;
            }
    }

    // ---- GEMM2 ----
    float4v acc2[2][8];
    #pragma unroll
    for (int ms = 0; ms < 2; ++ms)
        #pragma unroll
        for (int t = 0; t < 8; ++t) acc2[ms][t] = fzero;

    #pragma unroll
    for (int s = 0; s < 4; ++s) {
        half8 a2[2];
        #pragma unroll
        for (int ms = 0; ms < 2; ++ms)
            a2[ms] = *(const half8*)&s_act[act_idx64(4 * s + lhi, r0 + 16 * ms + llo, 0)];
        const int bbase = ((4 * s + lhi) * 128 + llo) << 3;
        #pragma unroll
        for (int t = 0; t < 8; ++t) {
            const half8 b = *(const half8*)(pw2 + bbase + (t << 7));
            acc2[0][t] = __builtin_amdgcn_mfma_f32_16x16x32_f16(a2[0], b, acc2[0][t], 0, 0, 0);
            acc2[1][t] = __builtin_amdgcn_mfma_f32_16x16x32_f16(a2[1], b, acc2[1][t], 0, 0, 0);
        }
    }

    #pragma unroll
    for (int t = 0; t < 8; ++t) {
        const int col = 16 * t + llo;
        const float b2 = mb2[col];
        #pragma unroll
        for (int ms = 0; ms < 2; ++ms)
            #pragma unroll
            for (int i = 0; i < 4; ++i) {
                const int row = r0 + 16 * ms + 4 * lhi + i;
                float v = gelu_tanh(acc2[ms][t][i] + b2);
                s_act[act_idx64(col >> 3, row, col & 7)] = (_Float16)v;
            }
    }

    // ---- GEMM3 ----
    float4v acc3[2][8];
    #pragma unroll
    for (int ms = 0; ms < 2; ++ms)
        #pragma unroll
        for (int t = 0; t < 8; ++t) acc3[ms][t] = fzero;

    #pragma unroll
    for (int s = 0; s < 4; ++s) {
        half8 a3[2];
        #pragma unroll
        for (int ms = 0; ms < 2; ++ms)
            a3[ms] = *(const half8*)&s_act[act_idx64(4 * s + lhi, r0 + 16 * ms + llo, 0)];
        const int bbase = ((4 * s + lhi) * 128 + llo) << 3;
        #pragma unroll
        for (int t = 0; t < 8; ++t) {
            const half8 b = *(const half8*)(pw3 + bbase + (t << 7));
            acc3[0][t] = __builtin_amdgcn_mfma_f32_16x16x32_f16(a3[0], b, acc3[0][t], 0, 0, 0);
            acc3[1][t] = __builtin_amdgcn_mfma_f32_16x16x32_f16(a3[1], b, acc3[1][t], 0, 0, 0);
        }
    }

    float mb3v[8];
    #pragma unroll
    for (int t = 0; t < 8; ++t) mb3v[t] = mb3[16 * t + llo];

    #pragma unroll
    for (int ms = 0; ms < 2; ++ms)
        #pragma unroll
        for (int i = 0; i < 4; ++i) {
            const int row = r0 + 16 * ms + 4 * lhi + i;
            if (ATOMIC) {
                const size_t dbase = (size_t)s_dst[row] * 128;
                #pragma unroll
                for (int t = 0; t < 8; ++t)
                    unsafeAtomicAdd(&agg[dbase + 16 * t + llo], acc3[ms][t][i] + mb3v[t]);
            } else {
                _Float16* mrow = msgs + (size_t)(e0 + row) * 128;
                #pragma unroll
                for (int t = 0; t < 8; ++t)
                    __builtin_nontemporal_store((_Float16)(acc3[ms][t][i] + mb3v[t]), mrow + 16 * t + llo);
            }
        }
}

// ---------------- Update MLP + residual + LayerNorm ----------------
__global__ __launch_bounds__(256) void upd_kernel(
    const float* __restrict__ h, const _Float16* __restrict__ hf16,
    const _Float16* __restrict__ pu1, const _Float16* __restrict__ pu2,
    const float* __restrict__ ub1, const float* __restrict__ ub2,
    const float* __restrict__ gamma, const float* __restrict__ beta,
    const float* __restrict__ agg, const float* __restrict__ cnt,
    float* __restrict__ out)
{
    __shared__ __align__(16) _Float16 s_act[16 * 128 * 8];

    const int tid = threadIdx.x;
    const int n0  = blockIdx.x * 128;
    const int w = tid >> 6, l = tid & 63, lhi = l >> 4, llo = l & 15;
    const int r0 = 32 * w;
    const float4v fzero = {0.0f, 0.0f, 0.0f, 0.0f};

    float rcp[2];
    size_t nodeOff[2];
    #pragma unroll
    for (int ms = 0; ms < 2; ++ms) {
        int node = n0 + r0 + 16 * ms + llo;
        if (node >= NN) node = NN - 1;
        nodeOff[ms] = (size_t)node * 128;
        rcp[ms] = 1.0f / (cnt[node] + 1e-8f);
    }

    // ---- GEMM U1: [hf16 | agg/cnt] @ uW1, s=0..7 ----
    float4v acc[2][8];
    #pragma unroll
    for (int ms = 0; ms < 2; ++ms)
        #pragma unroll
        for (int t = 0; t < 8; ++t) acc[ms][t] = fzero;

    #pragma unroll
    for (int s = 0; s < 8; ++s) {
        half8 af[2];
        #pragma unroll
        for (int ms = 0; ms < 2; ++ms) {
            if (s < 4) {
                af[ms] = *(const half8*)(hf16 + nodeOff[ms] + 32 * s + 8 * lhi);
            } else {
                const float* p = agg + nodeOff[ms] + 32 * (s - 4) + 8 * lhi;
                float4v x0 = *(const float4v*)p;
                float4v x1 = *(const float4v*)(p + 4);
                x0 *= rcp[ms]; x1 *= rcp[ms];
                af[ms] = cvt8(x0, x1);
            }
        }
        const int bbase = ((4 * s + lhi) * 128 + llo) << 3;
        #pragma unroll
        for (int t = 0; t < 8; ++t) {
            const half8 b = *(const half8*)(pu1 + bbase + (t << 7));
            acc[0][t] = __builtin_amdgcn_mfma_f32_16x16x32_f16(af[0], b, acc[0][t], 0, 0, 0);
            acc[1][t] = __builtin_amdgcn_mfma_f32_16x16x32_f16(af[1], b, acc[1][t], 0, 0, 0);
        }
    }

    #pragma unroll
    for (int t = 0; t < 8; ++t) {
        const int col = 16 * t + llo;
        const float b1 = ub1[col];
        #pragma unroll
        for (int ms = 0; ms < 2; ++ms)
            #pragma unroll
            for (int i = 0; i < 4; ++i) {
                const int row = r0 + 16 * ms + 4 * lhi + i;
                float v = gelu_tanh(acc[ms][t][i] + b1);
                s_act[act_idx(col >> 3, row, col & 7)] = (_Float16)v;
            }
    }

    float4v acc2[2][8];
    #pragma unroll
    for (int ms = 0; ms < 2; ++ms)
        #pragma unroll
        for (int t = 0; t < 8; ++t) acc2[ms][t] = fzero;

    #pragma unroll
    for (int s = 0; s < 4; ++s) {
        half8 af[2];
        #pragma unroll
        for (int ms = 0; ms < 2; ++ms)
            af[ms] = *(const half8*)&s_act[act_idx(4 * s + lhi, r0 + 16 * ms + llo, 0)];
        const int bbase = ((4 * s + lhi) * 128 + llo) << 3;
        #pragma unroll
        for (int t = 0; t < 8; ++t) {
            const half8 b = *(const half8*)(pu2 + bbase + (t << 7));
            acc2[0][t] = __builtin_amdgcn_mfma_f32_16x16x32_f16(af[0], b, acc2[0][t], 0, 0, 0);
            acc2[1][t] = __builtin_amdgcn_mfma_f32_16x16x32_f16(af[1], b, acc2[1][t], 0, 0, 0);
        }
    }

    float ub2v[8], gv[8], bv[8];
    #pragma unroll
    for (int t = 0; t < 8; ++t) {
        const int col = 16 * t + llo;
        ub2v[t] = ub2[col]; gv[t] = gamma[col]; bv[t] = beta[col];
    }

    #pragma unroll
    for (int ms = 0; ms < 2; ++ms)
        #pragma unroll
        for (int i = 0; i < 4; ++i) {
            const int noderow = n0 + r0 + 16 * ms + 4 * lhi + i;
            const int nodec = noderow < NN ? noderow : NN - 1;
            float y[8];
            float sum = 0.0f;
            #pragma unroll
            for (int t = 0; t < 8; ++t) {
                const int col = 16 * t + llo;
                float v = acc2[ms][t][i] + ub2v[t] + h[(size_t)nodec * 128 + col];
                y[t] = v; sum += v;
            }
            sum += __shfl_xor(sum, 1, 16);
            sum += __shfl_xor(sum, 2, 16);
            sum += __shfl_xor(sum, 4, 16);
            sum += __shfl_xor(sum, 8, 16);
            const float mu = sum * (1.0f / 128.0f);
            float sq = 0.0f;
            #pragma unroll
            for (int t = 0; t < 8; ++t) { float d = y[t] - mu; sq += d * d; }
            sq += __shfl_xor(sq, 1, 16);
            sq += __shfl_xor(sq, 2, 16);
            sq += __shfl_xor(sq, 4, 16);
            sq += __shfl_xor(sq, 8, 16);
            const float rs = rsqrtf(sq * (1.0f / 128.0f) + 1e-5f);
            if (noderow < NN) {
                #pragma unroll
                for (int t = 0; t < 8; ++t) {
                    const int col = 16 * t + llo;
                    out[(size_t)noderow * 128 + col] = (y[t] - mu) * rs * gv[t] + bv[t];
                }
            }
        }
}

extern "C" void kernel_launch(void* const* d_in, const int* in_sizes, int n_in,
                              void* d_out, int out_size, void* d_ws, size_t ws_size,
                              hipStream_t stream) {
    const float* h     = (const float*)d_in[0];
    const int*   ei    = (const int*)d_in[1];
    const float* eattr = (const float*)d_in[2];
    const float* mW1   = (const float*)d_in[3];
    const float* mb1   = (const float*)d_in[4];
    const float* mW2   = (const float*)d_in[5];
    const float* mb2   = (const float*)d_in[6];
    const float* mW3   = (const float*)d_in[7];
    const float* mb3   = (const float*)d_in[8];
    const float* uW1   = (const float*)d_in[9];
    const float* ub1   = (const float*)d_in[10];
    const float* uW2   = (const float*)d_in[11];
    const float* ub2   = (const float*)d_in[12];
    const float* gamma = (const float*)d_in[13];
    const float* beta  = (const float*)d_in[14];
    float* out = (float*)d_out;

    char* ws = (char*)d_ws;

    // Main layout (bytes)
    const size_t OFF_MSGS = 0;              // f16 600000*128*2 = 153,600,000
    const size_t OFF_AGG  = 153600000;      // f32 25,600,000
    const size_t OFF_HF   = 179200000;      // f16 12,800,000
    const size_t OFF_EF   = 192000000;      // f16 76,800,000
    const size_t OFF_CNTI = 268800000;      // 200,000
    const size_t OFF_CURS = 269000000;      // 200,000
    const size_t OFF_OFFS = 269200000;      // 200,004 (padded)
    const size_t OFF_PERM = 269400064;      // 2,400,000
    const size_t OFF_CNTF = 271800064;      // 200,000
    const size_t OFF_PW   = 272000064;      // 245,760
    const size_t NEED     = 272245824;

    if (ws_size >= NEED) {
        _Float16* msgs  = (_Float16*)(ws + OFF_MSGS);
        float* agg      = (float*)(ws + OFF_AGG);
        _Float16* hf16  = (_Float16*)(ws + OFF_HF);
        _Float16* ef16  = (_Float16*)(ws + OFF_EF);
        int* cnt_i      = (int*)(ws + OFF_CNTI);
        int* cursor     = (int*)(ws + OFF_CURS);
        int* offs       = (int*)(ws + OFF_OFFS);
        int* perm       = (int*)(ws + OFF_PERM);
        float* cntf     = (float*)(ws + OFF_CNTF);
        _Float16* pw    = (_Float16*)(ws + OFF_PW);
        _Float16* pw1 = pw;
        _Float16* pw2 = pw + 40960;
        _Float16* pw3 = pw + 57344;
        _Float16* pu1 = pw + 73728;
        _Float16* pu2 = pw + 106496;

        hipMemsetAsync(ws + OFF_CNTI, 0, 400000, stream);   // cnt_i + cursor

        pack_all<<<480, 256, 0, stream>>>(mW1, mW2, mW3, uW1, uW2, pw);
        cvt_pre<<<2048, 256, 0, stream>>>(h, eattr, hf16, ef16);
        count_kernel<<<(E_TOTAL + 255) / 256, 256, 0, stream>>>(ei, cnt_i);
        scan_kernel<<<1, 1024, 0, stream>>>(cnt_i, offs);
        fill_kernel<<<(E_TOTAL + 255) / 256, 256, 0, stream>>>(ei, offs, cursor, perm);

        msg_kernel<0><<<E_TOTAL / 64, 128, 0, stream>>>(
            hf16, ei, ef16, pw1, pw2, pw3, mb1, mb2, mb3, msgs, nullptr, nullptr);

        agg_kernel<<<NN / 4, 256, 0, stream>>>(msgs, offs, perm, agg, cntf);

        upd_kernel<<<(NN + 127) / 128, 256, 0, stream>>>(
            h, hf16, pu1, pu2, ub1, ub2, gamma, beta, agg, cntf, out);
    } else {
        // Fallback: atomic-scatter path (needs ~115.7 MB)
        float* agg     = (float*)ws;                       // 25,600,000
        float* cnt     = (float*)(ws + 25600000);          // 200,000
        _Float16* hf16 = (_Float16*)(ws + 25800000);       // 12,800,000
        _Float16* ef16 = (_Float16*)(ws + 38600000);       // 76,800,000
        _Float16* pw   = (_Float16*)(ws + 115400000);      // 245,760
        _Float16* pw1 = pw;
        _Float16* pw2 = pw + 40960;
        _Float16* pw3 = pw + 57344;
        _Float16* pu1 = pw + 73728;
        _Float16* pu2 = pw + 106496;

        hipMemsetAsync(ws, 0, 25800000, stream);

        pack_all<<<480, 256, 0, stream>>>(mW1, mW2, mW3, uW1, uW2, pw);
        cvt_pre<<<2048, 256, 0, stream>>>(h, eattr, hf16, ef16);

        msg_kernel<1><<<E_TOTAL / 64, 128, 0, stream>>>(
            hf16, ei, ef16, pw1, pw2, pw3, mb1, mb2, mb3, nullptr, agg, cnt);

        upd_kernel<<<(NN + 127) / 128, 256, 0, stream>>>(
            h, hf16, pu1, pu2, ub1, ub2, gamma, beta, agg, cnt, out);
    }
}

// Round 8
// 755.477 us; speedup vs baseline: 1.4380x; 1.1360x over previous
//
#include <hip/hip_runtime.h>

#define E_TOTAL 600000
#define NN 50000

typedef _Float16 half8 __attribute__((ext_vector_type(8)));
typedef _Float16 half2v __attribute__((ext_vector_type(2)));
typedef float float4v __attribute__((ext_vector_type(4)));
typedef float float2v __attribute__((ext_vector_type(2)));

__device__ __forceinline__ float gelu_tanh(float x) {
    // jax.nn.gelu approximate=True
    float u = 0.7978845608028654f * (x + 0.044715f * x * x * x);
    float ex = __expf(2.0f * u);
    float t = 1.0f - 2.0f / (ex + 1.0f);
    return 0.5f * x * (1.0f + t);
}

// 128-row activation LDS swizzle (upd kernel). Verified 0 conflicts R3/R5/R7.
__device__ __forceinline__ int act_idx(int c, int row, int q) {
    int idx = ((c * 128 + row) << 3) + q;
    idx ^= ((row >> 3) & 3) << 4;
    idx ^= (c & 1) << 3;
    return idx;
}
// 64-row variant (msg kernel, 2-wave blocks).
__device__ __forceinline__ int act_idx64(int c, int row, int q) {
    int idx = ((c * 64 + row) << 3) + q;
    idx ^= ((row >> 3) & 3) << 4;
    idx ^= (c & 1) << 3;
    return idx;
}

__device__ __forceinline__ half8 cvt8(float4v x0, float4v x1) {
    half8 a;
    a[0] = (_Float16)x0[0]; a[1] = (_Float16)x0[1]; a[2] = (_Float16)x0[2]; a[3] = (_Float16)x0[3];
    a[4] = (_Float16)x1[0]; a[5] = (_Float16)x1[1]; a[6] = (_Float16)x1[2]; a[7] = (_Float16)x1[3];
    return a;
}

// Pack W[K][128] f32 row-major into MFMA B-fragment order, f16.
__global__ __launch_bounds__(256) void pack_all(
    const float* __restrict__ mW1, const float* __restrict__ mW2, const float* __restrict__ mW3,
    const float* __restrict__ uW1, const float* __restrict__ uW2,
    _Float16* __restrict__ dst)
{
    int t = blockIdx.x * 256 + threadIdx.x;
    const float* src;
    int loc;
    if (t < 40960)        { src = mW1; loc = t; }
    else if (t < 57344)   { src = mW2; loc = t - 40960; }
    else if (t < 73728)   { src = mW3; loc = t - 57344; }
    else if (t < 106496)  { src = uW1; loc = t - 73728; }
    else if (t < 122880)  { src = uW2; loc = t - 106496; }
    else return;
    int i   = loc & 7;
    int col = (loc >> 3) & 127;
    int c   = loc >> 10;
    dst[t] = (_Float16)src[(8 * c + i) * 128 + col];
}

// Pre-convert h only (800000 8-elem chunks = 6.4M f32). eattr stays f32
// (converting it costs 230 MB of traffic to save 77 MB — net negative).
__global__ __launch_bounds__(256) void cvt_pre(
    const float* __restrict__ h, _Float16* __restrict__ hf)
{
    const int stride = gridDim.x * 256;
    for (int i = blockIdx.x * 256 + threadIdx.x; i < 800000; i += stride) {
        float4v a = ((const float4v*)h)[2 * i];
        float4v b = ((const float4v*)h)[2 * i + 1];
        ((half8*)hf)[i] = cvt8(a, b);
    }
}

// edge_index dtype probe: int64 viewed as int32 has all-zero odd words.
__device__ __forceinline__ int detect_i64(const int* ei) {
    int allz = 1;
    #pragma unroll
    for (int j = 1; j < 64; j += 2) allz &= (ei[j] == 0);
    return allz;
}

// ---------------- CSR build ----------------
__global__ __launch_bounds__(256) void count_kernel(const int* __restrict__ ei, int* __restrict__ cnt_i) {
    __shared__ int s_mode;
    if (threadIdx.x == 0) s_mode = detect_i64(ei);
    __syncthreads();
    int e = blockIdx.x * 256 + threadIdx.x;
    if (e >= E_TOTAL) return;
    int d = s_mode ? (int)((const long long*)ei)[E_TOTAL + e] : ei[E_TOTAL + e];
    atomicAdd(&cnt_i[d], 1);
}

__global__ __launch_bounds__(1024) void scan_kernel(const int* __restrict__ cnt_i, int* __restrict__ offs) {
    __shared__ int part[1024];
    const int t = threadIdx.x;
    const int PER = (NN + 1023) / 1024;   // 49
    const int base = t * PER;
    int s = 0;
    for (int j = 0; j < PER; ++j) { int idx = base + j; if (idx < NN) s += cnt_i[idx]; }
    part[t] = s;
    __syncthreads();
    for (int off = 1; off < 1024; off <<= 1) {
        int v = (t >= off) ? part[t - off] : 0;
        __syncthreads();
        part[t] += v;
        __syncthreads();
    }
    int run = (t == 0) ? 0 : part[t - 1];
    for (int j = 0; j < PER; ++j) { int idx = base + j; if (idx < NN) { offs[idx] = run; run += cnt_i[idx]; } }
    if (t == 1023) offs[NN] = part[1023];
}

__global__ __launch_bounds__(256) void fill_kernel(const int* __restrict__ ei, const int* __restrict__ offs,
                                                   int* __restrict__ cursor, int* __restrict__ perm) {
    __shared__ int s_mode;
    if (threadIdx.x == 0) s_mode = detect_i64(ei);
    __syncthreads();
    int e = blockIdx.x * 256 + threadIdx.x;
    if (e >= E_TOTAL) return;
    int d = s_mode ? (int)((const long long*)ei)[E_TOTAL + e] : ei[E_TOTAL + e];
    int pos = offs[d] + atomicAdd(&cursor[d], 1);
    perm[pos] = e;
}

// ---------------- aggregation: SEQUENTIAL gather-sum ----------------
// msgs are stored in dst-sorted slot order, so node's messages are rows
// [offs[node], offs[node+1]) — a contiguous stream. 4-wide unroll for MLP.
__global__ __launch_bounds__(256) void agg_kernel(const _Float16* __restrict__ msgs,
                                                  const int* __restrict__ offs,
                                                  float* __restrict__ agg, float* __restrict__ cntf) {
    const int node = blockIdx.x * 4 + (threadIdx.x >> 6);   // NN % 4 == 0
    const int l = threadIdx.x & 63;
    const int beg = offs[node], end = offs[node + 1];
    float2v s = {0.0f, 0.0f};
    const half2v* p = (const half2v*)msgs + (size_t)beg * 64 + l;
    int j = beg;
    for (; j + 3 < end; j += 4, p += 256) {
        half2v a = __builtin_nontemporal_load(p);
        half2v b = __builtin_nontemporal_load(p + 64);
        half2v c = __builtin_nontemporal_load(p + 128);
        half2v d = __builtin_nontemporal_load(p + 192);
        s.x += (float)a[0] + (float)b[0] + (float)c[0] + (float)d[0];
        s.y += (float)a[1] + (float)b[1] + (float)c[1] + (float)d[1];
    }
    for (; j < end; ++j, p += 64) {
        half2v v = __builtin_nontemporal_load(p);
        s.x += (float)v[0]; s.y += (float)v[1];
    }
    ((float2v*)agg)[(size_t)node * 64 + l] = s;
    if (l == 0) cntf[node] = (float)(end - beg);
}

// ---------------- Message MLP (dst-sorted edge order) ----------------
// 128 threads = 2 waves; 64 edge-slots/block (600000/64 = 9375 exact).
// Slot q holds edge perm[q]; msgs row q is written sequentially (slot order),
// so agg_kernel streams. dst-gathers of h are block-clustered (L2 hits).
// A-operands: h f16 (4-deep prefetch rotation), eattr f32 direct + in-reg cvt.
// ATOMIC=1 fallback: f32-atomic scatter into agg + cnt staging atomic.
template<int ATOMIC>
__global__ __launch_bounds__(128, 3) void msg_kernel(
    const _Float16* __restrict__ hf16, const int* __restrict__ ei, const float* __restrict__ eattr,
    const int* __restrict__ perm,
    const _Float16* __restrict__ pw1, const _Float16* __restrict__ pw2, const _Float16* __restrict__ pw3,
    const float* __restrict__ mb1, const float* __restrict__ mb2, const float* __restrict__ mb3,
    _Float16* __restrict__ msgs, float* __restrict__ agg, float* __restrict__ cnt)
{
    __shared__ int s_e[64];
    __shared__ int s_src[64];
    __shared__ int s_dst[64];
    __shared__ int s_mode;
    __shared__ __align__(16) _Float16 s_act[16 * 64 * 8];   // 16 KB

    const int tid = threadIdx.x;
    const int e0  = blockIdx.x * 64;

    if (tid == 0) s_mode = detect_i64(ei);
    __syncthreads();

    if (tid < 64) {
        int e = perm[e0 + tid];
        s_e[tid] = e;
        int srcn, dstn;
        if (s_mode) {
            const long long* e64 = (const long long*)ei;
            srcn = (int)e64[e];
            dstn = (int)e64[E_TOTAL + e];
        } else {
            srcn = ei[e];
            dstn = ei[E_TOTAL + e];
        }
        s_src[tid] = srcn;
        s_dst[tid] = dstn;
        if (ATOMIC) unsafeAtomicAdd(&cnt[dstn], 1.0f);
    }
    __syncthreads();

    const int w = tid >> 6, l = tid & 63, lhi = l >> 4, llo = l & 15;
    const int r0 = 32 * w;
    const float4v fzero = {0.0f, 0.0f, 0.0f, 0.0f};

    // Per-lane A-row base pointers (rows r0+llo, r0+16+llo)
    const _Float16* srcP[2];
    const _Float16* dstP[2];
    const float*    eP[2];
    #pragma unroll
    for (int ms = 0; ms < 2; ++ms) {
        const int row = r0 + 16 * ms + llo;
        srcP[ms] = hf16 + (size_t)s_src[row] * 128 + 8 * lhi;
        dstP[ms] = hf16 + (size_t)s_dst[row] * 128 + 8 * lhi;
        eP[ms]   = eattr + (size_t)s_e[row] * 64 + 8 * lhi;
    }

    // ---- GEMM1: X[64][320] @ W1 (s=0..9), 4-deep A prefetch ----
    // K map: s=0..3 h[src], s=4..7 h[dst] (f16); s=8..9 eattr (f32, cvt).
    float4v acc[2][8];
    #pragma unroll
    for (int ms = 0; ms < 2; ++ms)
        #pragma unroll
        for (int t = 0; t < 8; ++t) acc[ms][t] = fzero;

    half8 af[4][2];
    #pragma unroll
    for (int s = 0; s < 4; ++s)
        #pragma unroll
        for (int ms = 0; ms < 2; ++ms)
            af[s][ms] = *(const half8*)(srcP[ms] + 32 * s);

    #pragma unroll
    for (int s = 0; s < 10; ++s) {
        const int bbase = ((4 * s + lhi) * 128 + llo) << 3;
        #pragma unroll
        for (int t = 0; t < 8; ++t) {
            const half8 b = *(const half8*)(pw1 + bbase + (t << 7));
            acc[0][t] = __builtin_amdgcn_mfma_f32_16x16x32_f16(af[s & 3][0], b, acc[0][t], 0, 0, 0);
            acc[1][t] = __builtin_amdgcn_mfma_f32_16x16x32_f16(af[s & 3][1], b, acc[1][t], 0, 0, 0);
        }
        if (s + 4 <= 9) {
            const int sn = s + 4;
            #pragma unroll
            for (int ms = 0; ms < 2; ++ms) {
                if (sn < 8) {
                    af[sn & 3][ms] = *(const half8*)(dstP[ms] + 32 * (sn - 4));
                } else {
                    const float* p = eP[ms] + 32 * (sn - 8);
                    float4v x0 = *(const float4v*)p;
                    float4v x1 = *(const float4v*)(p + 4);
                    af[sn & 3][ms] = cvt8(x0, x1);
                }
            }
        }
    }

    // E1: bias + gelu -> s_act
    #pragma unroll
    for (int t = 0; t < 8; ++t) {
        const int col = 16 * t + llo;
        const float b1 = mb1[col];
        #pragma unroll
        for (int ms = 0; ms < 2; ++ms)
            #pragma unroll
            for (int i = 0; i < 4; ++i) {
                const int row = r0 + 16 * ms + 4 * lhi + i;
                float v = gelu_tanh(acc[ms][t][i] + b1);
                s_act[act_idx64(col >> 3, row, col & 7)] = (_Float16)v;
            }
    }

    // ---- GEMM2 ----
    float4v acc2[2][8];
    #pragma unroll
    for (int ms = 0; ms < 2; ++ms)
        #pragma unroll
        for (int t = 0; t < 8; ++t) acc2[ms][t] = fzero;

    #pragma unroll
    for (int s = 0; s < 4; ++s) {
        half8 a2[2];
        #pragma unroll
        for (int ms = 0; ms < 2; ++ms)
            a2[ms] = *(const half8*)&s_act[act_idx64(4 * s + lhi, r0 + 16 * ms + llo, 0)];
        const int bbase = ((4 * s + lhi) * 128 + llo) << 3;
        #pragma unroll
        for (int t = 0; t < 8; ++t) {
            const half8 b = *(const half8*)(pw2 + bbase + (t << 7));
            acc2[0][t] = __builtin_amdgcn_mfma_f32_16x16x32_f16(a2[0], b, acc2[0][t], 0, 0, 0);
            acc2[1][t] = __builtin_amdgcn_mfma_f32_16x16x32_f16(a2[1], b, acc2[1][t], 0, 0, 0);
        }
    }

    #pragma unroll
    for (int t = 0; t < 8; ++t) {
        const int col = 16 * t + llo;
        const float b2 = mb2[col];
        #pragma unroll
        for (int ms = 0; ms < 2; ++ms)
            #pragma unroll
            for (int i = 0; i < 4; ++i) {
                const int row = r0 + 16 * ms + 4 * lhi + i;
                float v = gelu_tanh(acc2[ms][t][i] + b2);
                s_act[act_idx64(col >> 3, row, col & 7)] = (_Float16)v;
            }
    }

    // ---- GEMM3 ----
    float4v acc3[2][8];
    #pragma unroll
    for (int ms = 0; ms < 2; ++ms)
        #pragma unroll
        for (int t = 0; t < 8; ++t) acc3[ms][t] = fzero;

    #pragma unroll
    for (int s = 0; s < 4; ++s) {
        half8 a3[2];
        #pragma unroll
        for (int ms = 0; ms < 2; ++ms)
            a3[ms] = *(const half8*)&s_act[act_idx64(4 * s + lhi, r0 + 16 * ms + llo, 0)];
        const int bbase = ((4 * s + lhi) * 128 + llo) << 3;
        #pragma unroll
        for (int t = 0; t < 8; ++t) {
            const half8 b = *(const half8*)(pw3 + bbase + (t << 7));
            acc3[0][t] = __builtin_amdgcn_mfma_f32_16x16x32_f16(a3[0], b, acc3[0][t], 0, 0, 0);
            acc3[1][t] = __builtin_amdgcn_mfma_f32_16x16x32_f16(a3[1], b, acc3[1][t], 0, 0, 0);
        }
    }

    float mb3v[8];
    #pragma unroll
    for (int t = 0; t < 8; ++t) mb3v[t] = mb3[16 * t + llo];

    #pragma unroll
    for (int ms = 0; ms < 2; ++ms)
        #pragma unroll
        for (int i = 0; i < 4; ++i) {
            const int row = r0 + 16 * ms + 4 * lhi + i;
            if (ATOMIC) {
                const size_t dbase = (size_t)s_dst[row] * 128;
                #pragma unroll
                for (int t = 0; t < 8; ++t)
                    unsafeAtomicAdd(&agg[dbase + 16 * t + llo], acc3[ms][t][i] + mb3v[t]);
            } else {
                // slot-order (sorted) sequential store
                _Float16* mrow = msgs + (size_t)(e0 + row) * 128;
                #pragma unroll
                for (int t = 0; t < 8; ++t)
                    __builtin_nontemporal_store((_Float16)(acc3[ms][t][i] + mb3v[t]), mrow + 16 * t + llo);
            }
        }
}

// ---------------- Update MLP + residual + LayerNorm ----------------
__global__ __launch_bounds__(256) void upd_kernel(
    const float* __restrict__ h, const _Float16* __restrict__ hf16,
    const _Float16* __restrict__ pu1, const _Float16* __restrict__ pu2,
    const float* __restrict__ ub1, const float* __restrict__ ub2,
    const float* __restrict__ gamma, const float* __restrict__ beta,
    const float* __restrict__ agg, const float* __restrict__ cnt,
    float* __restrict__ out)
{
    __shared__ __align__(16) _Float16 s_act[16 * 128 * 8];

    const int tid = threadIdx.x;
    const int n0  = blockIdx.x * 128;
    const int w = tid >> 6, l = tid & 63, lhi = l >> 4, llo = l & 15;
    const int r0 = 32 * w;
    const float4v fzero = {0.0f, 0.0f, 0.0f, 0.0f};

    float rcp[2];
    size_t nodeOff[2];
    #pragma unroll
    for (int ms = 0; ms < 2; ++ms) {
        int node = n0 + r0 + 16 * ms + llo;
        if (node >= NN) node = NN - 1;
        nodeOff[ms] = (size_t)node * 128;
        rcp[ms] = 1.0f / (cnt[node] + 1e-8f);
    }

    float4v acc[2][8];
    #pragma unroll
    for (int ms = 0; ms < 2; ++ms)
        #pragma unroll
        for (int t = 0; t < 8; ++t) acc[ms][t] = fzero;

    #pragma unroll
    for (int s = 0; s < 8; ++s) {
        half8 af[2];
        #pragma unroll
        for (int ms = 0; ms < 2; ++ms) {
            if (s < 4) {
                af[ms] = *(const half8*)(hf16 + nodeOff[ms] + 32 * s + 8 * lhi);
            } else {
                const float* p = agg + nodeOff[ms] + 32 * (s - 4) + 8 * lhi;
                float4v x0 = *(const float4v*)p;
                float4v x1 = *(const float4v*)(p + 4);
                x0 *= rcp[ms]; x1 *= rcp[ms];
                af[ms] = cvt8(x0, x1);
            }
        }
        const int bbase = ((4 * s + lhi) * 128 + llo) << 3;
        #pragma unroll
        for (int t = 0; t < 8; ++t) {
            const half8 b = *(const half8*)(pu1 + bbase + (t << 7));
            acc[0][t] = __builtin_amdgcn_mfma_f32_16x16x32_f16(af[0], b, acc[0][t], 0, 0, 0);
            acc[1][t] = __builtin_amdgcn_mfma_f32_16x16x32_f16(af[1], b, acc[1][t], 0, 0, 0);
        }
    }

    #pragma unroll
    for (int t = 0; t < 8; ++t) {
        const int col = 16 * t + llo;
        const float b1 = ub1[col];
        #pragma unroll
        for (int ms = 0; ms < 2; ++ms)
            #pragma unroll
            for (int i = 0; i < 4; ++i) {
                const int row = r0 + 16 * ms + 4 * lhi + i;
                float v = gelu_tanh(acc[ms][t][i] + b1);
                s_act[act_idx(col >> 3, row, col & 7)] = (_Float16)v;
            }
    }

    float4v acc2[2][8];
    #pragma unroll
    for (int ms = 0; ms < 2; ++ms)
        #pragma unroll
        for (int t = 0; t < 8; ++t) acc2[ms][t] = fzero;

    #pragma unroll
    for (int s = 0; s < 4; ++s) {
        half8 af[2];
        #pragma unroll
        for (int ms = 0; ms < 2; ++ms)
            af[ms] = *(const half8*)&s_act[act_idx(4 * s + lhi, r0 + 16 * ms + llo, 0)];
        const int bbase = ((4 * s + lhi) * 128 + llo) << 3;
        #pragma unroll
        for (int t = 0; t < 8; ++t) {
            const half8 b = *(const half8*)(pu2 + bbase + (t << 7));
            acc2[0][t] = __builtin_amdgcn_mfma_f32_16x16x32_f16(af[0], b, acc2[0][t], 0, 0, 0);
            acc2[1][t] = __builtin_amdgcn_mfma_f32_16x16x32_f16(af[1], b, acc2[1][t], 0, 0, 0);
        }
    }

    float ub2v[8], gv[8], bv[8];
    #pragma unroll
    for (int t = 0; t < 8; ++t) {
        const int col = 16 * t + llo;
        ub2v[t] = ub2[col]; gv[t] = gamma[col]; bv[t] = beta[col];
    }

    #pragma unroll
    for (int ms = 0; ms < 2; ++ms)
        #pragma unroll
        for (int i = 0; i < 4; ++i) {
            const int noderow = n0 + r0 + 16 * ms + 4 * lhi + i;
            const int nodec = noderow < NN ? noderow : NN - 1;
            float y[8];
            float sum = 0.0f;
            #pragma unroll
            for (int t = 0; t < 8; ++t) {
                const int col = 16 * t + llo;
                float v = acc2[ms][t][i] + ub2v[t] + h[(size_t)nodec * 128 + col];
                y[t] = v; sum += v;
            }
            sum += __shfl_xor(sum, 1, 16);
            sum += __shfl_xor(sum, 2, 16);
            sum += __shfl_xor(sum, 4, 16);
            sum += __shfl_xor(sum, 8, 16);
            const float mu = sum * (1.0f / 128.0f);
            float sq = 0.0f;
            #pragma unroll
            for (int t = 0; t < 8; ++t) { float d = y[t] - mu; sq += d * d; }
            sq += __shfl_xor(sq, 1, 16);
            sq += __shfl_xor(sq, 2, 16);
            sq += __shfl_xor(sq, 4, 16);
            sq += __shfl_xor(sq, 8, 16);
            const float rs = rsqrtf(sq * (1.0f / 128.0f) + 1e-5f);
            if (noderow < NN) {
                #pragma unroll
                for (int t = 0; t < 8; ++t) {
                    const int col = 16 * t + llo;
                    out[(size_t)noderow * 128 + col] = (y[t] - mu) * rs * gv[t] + bv[t];
                }
            }
        }
}

extern "C" void kernel_launch(void* const* d_in, const int* in_sizes, int n_in,
                              void* d_out, int out_size, void* d_ws, size_t ws_size,
                              hipStream_t stream) {
    const float* h     = (const float*)d_in[0];
    const int*   ei    = (const int*)d_in[1];
    const float* eattr = (const float*)d_in[2];
    const float* mW1   = (const float*)d_in[3];
    const float* mb1   = (const float*)d_in[4];
    const float* mW2   = (const float*)d_in[5];
    const float* mb2   = (const float*)d_in[6];
    const float* mW3   = (const float*)d_in[7];
    const float* mb3   = (const float*)d_in[8];
    const float* uW1   = (const float*)d_in[9];
    const float* ub1   = (const float*)d_in[10];
    const float* uW2   = (const float*)d_in[11];
    const float* ub2   = (const float*)d_in[12];
    const float* gamma = (const float*)d_in[13];
    const float* beta  = (const float*)d_in[14];
    float* out = (float*)d_out;

    char* ws = (char*)d_ws;

    // Main layout (bytes)
    const size_t OFF_MSGS = 0;              // f16 600000*128*2 = 153,600,000
    const size_t OFF_AGG  = 153600000;      // f32 25,600,000
    const size_t OFF_HF   = 179200000;      // f16 12,800,000
    const size_t OFF_CNTI = 192000000;      // 200,000
    const size_t OFF_CURS = 192200000;      // 200,000
    const size_t OFF_OFFS = 192400000;      // 200,004 (padded)
    const size_t OFF_PERM = 192600064;      // 2,400,000
    const size_t OFF_CNTF = 195000064;      // 200,000
    const size_t OFF_PW   = 195200064;      // 245,760
    const size_t NEED     = 195445824;

    if (ws_size >= NEED) {
        _Float16* msgs  = (_Float16*)(ws + OFF_MSGS);
        float* agg      = (float*)(ws + OFF_AGG);
        _Float16* hf16  = (_Float16*)(ws + OFF_HF);
        int* cnt_i      = (int*)(ws + OFF_CNTI);
        int* cursor     = (int*)(ws + OFF_CURS);
        int* offs       = (int*)(ws + OFF_OFFS);
        int* perm       = (int*)(ws + OFF_PERM);
        float* cntf     = (float*)(ws + OFF_CNTF);
        _Float16* pw    = (_Float16*)(ws + OFF_PW);
        _Float16* pw1 = pw;
        _Float16* pw2 = pw + 40960;
        _Float16* pw3 = pw + 57344;
        _Float16* pu1 = pw + 73728;
        _Float16* pu2 = pw + 106496;

        hipMemsetAsync(ws + OFF_CNTI, 0, 400000, stream);   // cnt_i + cursor

        count_kernel<<<(E_TOTAL + 255) / 256, 256, 0, stream>>>(ei, cnt_i);
        scan_kernel<<<1, 1024, 0, stream>>>(cnt_i, offs);
        fill_kernel<<<(E_TOTAL + 255) / 256, 256, 0, stream>>>(ei, offs, cursor, perm);
        pack_all<<<480, 256, 0, stream>>>(mW1, mW2, mW3, uW1, uW2, pw);
        cvt_pre<<<1024, 256, 0, stream>>>(h, hf16);

        msg_kernel<0><<<E_TOTAL / 64, 128, 0, stream>>>(
            hf16, ei, eattr, perm, pw1, pw2, pw3, mb1, mb2, mb3, msgs, nullptr, nullptr);

        agg_kernel<<<NN / 4, 256, 0, stream>>>(msgs, offs, agg, cntf);

        upd_kernel<<<(NN + 127) / 128, 256, 0, stream>>>(
            h, hf16, pu1, pu2, ub1, ub2, gamma, beta, agg, cntf, out);
    } else {
        // Fallback: atomic-scatter path (~42 MB). Still uses sorted order for
        // atomic locality; CSR buffers are small.
        float* agg     = (float*)ws;                       // 25,600,000
        float* cnt     = (float*)(ws + 25600000);          // 200,000
        _Float16* hf16 = (_Float16*)(ws + 25800000);       // 12,800,000
        int* cnt_i     = (int*)(ws + 38600000);            // 200,000
        int* cursor    = (int*)(ws + 38800000);            // 200,000
        int* offs      = (int*)(ws + 39000000);            // 200,004 (padded)
        int* perm      = (int*)(ws + 39200064);            // 2,400,000
        _Float16* pw   = (_Float16*)(ws + 41600064);       // 245,760
        _Float16* pw1 = pw;
        _Float16* pw2 = pw + 40960;
        _Float16* pw3 = pw + 57344;
        _Float16* pu1 = pw + 73728;
        _Float16* pu2 = pw + 106496;

        hipMemsetAsync(ws, 0, 25800000, stream);           // agg + cnt
        hipMemsetAsync(ws + 38600000, 0, 400000, stream);  // cnt_i + cursor

        count_kernel<<<(E_TOTAL + 255) / 256, 256, 0, stream>>>(ei, cnt_i);
        scan_kernel<<<1, 1024, 0, stream>>>(cnt_i, offs);
        fill_kernel<<<(E_TOTAL + 255) / 256, 256, 0, stream>>>(ei, offs, cursor, perm);
        pack_all<<<480, 256, 0, stream>>>(mW1, mW2, mW3, uW1, uW2, pw);
        cvt_pre<<<1024, 256, 0, stream>>>(h, hf16);

        msg_kernel<1><<<E_TOTAL / 64, 128, 0, stream>>>(
            hf16, ei, eattr, perm, pw1, pw2, pw3, mb1, mb2, mb3, nullptr, agg, cnt);

        upd_kernel<<<(NN + 127) / 128, 256, 0, stream>>>(
            h, hf16, pu1, pu2, ub1, ub2, gamma, beta, agg, cnt, out);
    }
}

// Round 9
// 716.557 us; speedup vs baseline: 1.5161x; 1.0543x over previous
//
#include <hip/hip_runtime.h>

#define E_TOTAL 600000
#define NN 50000

typedef _Float16 half8 __attribute__((ext_vector_type(8)));
typedef _Float16 half2v __attribute__((ext_vector_type(2)));
typedef float float4v __attribute__((ext_vector_type(4)));
typedef float float2v __attribute__((ext_vector_type(2)));

// gelu(x) = 0.5x(1+tanh(0.79788456(x+0.044715x^3))) = x*sigmoid(2u)
//         = x - x * rcp(exp(2u)+1),  2u = x*(A + B*x^2)
// v_rcp_f32 (~1e-7 rel err) replaces the f32 division (7-op sequence).
__device__ __forceinline__ float gelu_tanh(float x) {
    const float A = 1.5957691216057308f;
    const float B = 0.0713548163f;
    float z = x * __builtin_fmaf(B, x * x, A);
    float ex = __expf(z);                       // saturates: inf -> gelu=x, 0 -> gelu=0
    float r = __builtin_amdgcn_rcpf(ex + 1.0f);
    return __builtin_fmaf(-x, r, x);
}

// 128-row activation LDS swizzle (upd kernel). Verified 0 conflicts R3/R5/R7/R8.
__device__ __forceinline__ int act_idx(int c, int row, int q) {
    int idx = ((c * 128 + row) << 3) + q;
    idx ^= ((row >> 3) & 3) << 4;
    idx ^= (c & 1) << 3;
    return idx;
}
// 64-row variant (msg kernel, 2-wave blocks).
__device__ __forceinline__ int act_idx64(int c, int row, int q) {
    int idx = ((c * 64 + row) << 3) + q;
    idx ^= ((row >> 3) & 3) << 4;
    idx ^= (c & 1) << 3;
    return idx;
}

__device__ __forceinline__ half8 cvt8(float4v x0, float4v x1) {
    half8 a;
    a[0] = (_Float16)x0[0]; a[1] = (_Float16)x0[1]; a[2] = (_Float16)x0[2]; a[3] = (_Float16)x0[3];
    a[4] = (_Float16)x1[0]; a[5] = (_Float16)x1[1]; a[6] = (_Float16)x1[2]; a[7] = (_Float16)x1[3];
    return a;
}

// Merged prep: pack 5 weight mats into MFMA B-fragment f16 order (122880 items)
// + convert h f32->f16 (800000 8-elem chunks).
__global__ __launch_bounds__(256) void prep_kernel(
    const float* __restrict__ mW1, const float* __restrict__ mW2, const float* __restrict__ mW3,
    const float* __restrict__ uW1, const float* __restrict__ uW2,
    const float* __restrict__ h,
    _Float16* __restrict__ pw, _Float16* __restrict__ hf)
{
    const int stride = gridDim.x * 256;
    for (int t = blockIdx.x * 256 + threadIdx.x; t < 922880; t += stride) {
        if (t < 122880) {
            const float* src;
            int loc;
            if (t < 40960)        { src = mW1; loc = t; }
            else if (t < 57344)   { src = mW2; loc = t - 40960; }
            else if (t < 73728)   { src = mW3; loc = t - 57344; }
            else if (t < 106496)  { src = uW1; loc = t - 73728; }
            else                  { src = uW2; loc = t - 106496; }
            int i   = loc & 7;
            int col = (loc >> 3) & 127;
            int c   = loc >> 10;
            pw[t] = (_Float16)src[(8 * c + i) * 128 + col];
        } else {
            int i = t - 122880;
            float4v a = ((const float4v*)h)[2 * i];
            float4v b = ((const float4v*)h)[2 * i + 1];
            ((half8*)hf)[i] = cvt8(a, b);
        }
    }
}

// edge_index dtype probe: int64 viewed as int32 has all-zero odd words.
__device__ __forceinline__ int detect_i64(const int* ei) {
    int allz = 1;
    #pragma unroll
    for (int j = 1; j < 64; j += 2) allz &= (ei[j] == 0);
    return allz;
}

// ---------------- CSR build ----------------
__global__ __launch_bounds__(256) void count_kernel(const int* __restrict__ ei, int* __restrict__ cnt_i) {
    __shared__ int s_mode;
    if (threadIdx.x == 0) s_mode = detect_i64(ei);
    __syncthreads();
    int e = blockIdx.x * 256 + threadIdx.x;
    if (e >= E_TOTAL) return;
    int d = s_mode ? (int)((const long long*)ei)[E_TOTAL + e] : ei[E_TOTAL + e];
    atomicAdd(&cnt_i[d], 1);
}

__global__ __launch_bounds__(1024) void scan_kernel(const int* __restrict__ cnt_i, int* __restrict__ offs) {
    __shared__ int part[1024];
    const int t = threadIdx.x;
    const int PER = (NN + 1023) / 1024;   // 49
    const int base = t * PER;
    int s = 0;
    for (int j = 0; j < PER; ++j) { int idx = base + j; if (idx < NN) s += cnt_i[idx]; }
    part[t] = s;
    __syncthreads();
    for (int off = 1; off < 1024; off <<= 1) {
        int v = (t >= off) ? part[t - off] : 0;
        __syncthreads();
        part[t] += v;
        __syncthreads();
    }
    int run = (t == 0) ? 0 : part[t - 1];
    for (int j = 0; j < PER; ++j) { int idx = base + j; if (idx < NN) { offs[idx] = run; run += cnt_i[idx]; } }
    if (t == 1023) offs[NN] = part[1023];
}

__global__ __launch_bounds__(256) void fill_kernel(const int* __restrict__ ei, const int* __restrict__ offs,
                                                   int* __restrict__ cursor, int* __restrict__ perm) {
    __shared__ int s_mode;
    if (threadIdx.x == 0) s_mode = detect_i64(ei);
    __syncthreads();
    int e = blockIdx.x * 256 + threadIdx.x;
    if (e >= E_TOTAL) return;
    int d = s_mode ? (int)((const long long*)ei)[E_TOTAL + e] : ei[E_TOTAL + e];
    int pos = offs[d] + atomicAdd(&cursor[d], 1);
    perm[pos] = e;
}

// ---------------- Message MLP (dst-sorted edge order) ----------------
// 128 threads = 2 waves; 64 edge-slots/block (600000/64 = 9375 exact).
// Slot q holds edge perm[q]; msgs row q written sequentially (slot order).
// A-operands: h f16 (4-deep prefetch rotation), eattr f32 direct + in-reg cvt.
// ATOMIC=1 fallback: f32-atomic scatter into agg + cnt staging atomic.
template<int ATOMIC>
__global__ __launch_bounds__(128, 3) void msg_kernel(
    const _Float16* __restrict__ hf16, const int* __restrict__ ei, const float* __restrict__ eattr,
    const int* __restrict__ perm,
    const _Float16* __restrict__ pw1, const _Float16* __restrict__ pw2, const _Float16* __restrict__ pw3,
    const float* __restrict__ mb1, const float* __restrict__ mb2, const float* __restrict__ mb3,
    _Float16* __restrict__ msgs, float* __restrict__ agg, float* __restrict__ cnt)
{
    __shared__ int s_e[64];
    __shared__ int s_src[64];
    __shared__ int s_dst[64];
    __shared__ int s_mode;
    __shared__ __align__(16) _Float16 s_act[16 * 64 * 8];   // 16 KB

    const int tid = threadIdx.x;
    const int e0  = blockIdx.x * 64;

    if (tid == 0) s_mode = detect_i64(ei);
    __syncthreads();

    if (tid < 64) {
        int e = perm[e0 + tid];
        s_e[tid] = e;
        int srcn, dstn;
        if (s_mode) {
            const long long* e64 = (const long long*)ei;
            srcn = (int)e64[e];
            dstn = (int)e64[E_TOTAL + e];
        } else {
            srcn = ei[e];
            dstn = ei[E_TOTAL + e];
        }
        s_src[tid] = srcn;
        s_dst[tid] = dstn;
        if (ATOMIC) unsafeAtomicAdd(&cnt[dstn], 1.0f);
    }
    __syncthreads();

    const int w = tid >> 6, l = tid & 63, lhi = l >> 4, llo = l & 15;
    const int r0 = 32 * w;
    const float4v fzero = {0.0f, 0.0f, 0.0f, 0.0f};

    const _Float16* srcP[2];
    const _Float16* dstP[2];
    const float*    eP[2];
    #pragma unroll
    for (int ms = 0; ms < 2; ++ms) {
        const int row = r0 + 16 * ms + llo;
        srcP[ms] = hf16 + (size_t)s_src[row] * 128 + 8 * lhi;
        dstP[ms] = hf16 + (size_t)s_dst[row] * 128 + 8 * lhi;
        eP[ms]   = eattr + (size_t)s_e[row] * 64 + 8 * lhi;
    }

    // ---- GEMM1: X[64][320] @ W1 (s=0..9), 4-deep A prefetch ----
    float4v acc[2][8];
    #pragma unroll
    for (int ms = 0; ms < 2; ++ms)
        #pragma unroll
        for (int t = 0; t < 8; ++t) acc[ms][t] = fzero;

    half8 af[4][2];
    #pragma unroll
    for (int s = 0; s < 4; ++s)
        #pragma unroll
        for (int ms = 0; ms < 2; ++ms)
            af[s][ms] = *(const half8*)(srcP[ms] + 32 * s);

    #pragma unroll
    for (int s = 0; s < 10; ++s) {
        const int bbase = ((4 * s + lhi) * 128 + llo) << 3;
        #pragma unroll
        for (int t = 0; t < 8; ++t) {
            const half8 b = *(const half8*)(pw1 + bbase + (t << 7));
            acc[0][t] = __builtin_amdgcn_mfma_f32_16x16x32_f16(af[s & 3][0], b, acc[0][t], 0, 0, 0);
            acc[1][t] = __builtin_amdgcn_mfma_f32_16x16x32_f16(af[s & 3][1], b, acc[1][t], 0, 0, 0);
        }
        if (s + 4 <= 9) {
            const int sn = s + 4;
            #pragma unroll
            for (int ms = 0; ms < 2; ++ms) {
                if (sn < 8) {
                    af[sn & 3][ms] = *(const half8*)(dstP[ms] + 32 * (sn - 4));
                } else {
                    const float* p = eP[ms] + 32 * (sn - 8);
                    float4v x0 = *(const float4v*)p;
                    float4v x1 = *(const float4v*)(p + 4);
                    af[sn & 3][ms] = cvt8(x0, x1);
                }
            }
        }
    }

    // E1: bias + gelu -> s_act
    #pragma unroll
    for (int t = 0; t < 8; ++t) {
        const int col = 16 * t + llo;
        const float b1 = mb1[col];
        #pragma unroll
        for (int ms = 0; ms < 2; ++ms)
            #pragma unroll
            for (int i = 0; i < 4; ++i) {
                const int row = r0 + 16 * ms + 4 * lhi + i;
                float v = gelu_tanh(acc[ms][t][i] + b1);
                s_act[act_idx64(col >> 3, row, col & 7)] = (_Float16)v;
            }
    }

    // ---- GEMM2 ----
    float4v acc2[2][8];
    #pragma unroll
    for (int ms = 0; ms < 2; ++ms)
        #pragma unroll
        for (int t = 0; t < 8; ++t) acc2[ms][t] = fzero;

    #pragma unroll
    for (int s = 0; s < 4; ++s) {
        half8 a2[2];
        #pragma unroll
        for (int ms = 0; ms < 2; ++ms)
            a2[ms] = *(const half8*)&s_act[act_idx64(4 * s + lhi, r0 + 16 * ms + llo, 0)];
        const int bbase = ((4 * s + lhi) * 128 + llo) << 3;
        #pragma unroll
        for (int t = 0; t < 8; ++t) {
            const half8 b = *(const half8*)(pw2 + bbase + (t << 7));
            acc2[0][t] = __builtin_amdgcn_mfma_f32_16x16x32_f16(a2[0], b, acc2[0][t], 0, 0, 0);
            acc2[1][t] = __builtin_amdgcn_mfma_f32_16x16x32_f16(a2[1], b, acc2[1][t], 0, 0, 0);
        }
    }

    #pragma unroll
    for (int t = 0; t < 8; ++t) {
        const int col = 16 * t + llo;
        const float b2 = mb2[col];
        #pragma unroll
        for (int ms = 0; ms < 2; ++ms)
            #pragma unroll
            for (int i = 0; i < 4; ++i) {
                const int row = r0 + 16 * ms + 4 * lhi + i;
                float v = gelu_tanh(acc2[ms][t][i] + b2);
                s_act[act_idx64(col >> 3, row, col & 7)] = (_Float16)v;
            }
    }

    // ---- GEMM3 ----
    float4v acc3[2][8];
    #pragma unroll
    for (int ms = 0; ms < 2; ++ms)
        #pragma unroll
        for (int t = 0; t < 8; ++t) acc3[ms][t] = fzero;

    #pragma unroll
    for (int s = 0; s < 4; ++s) {
        half8 a3[2];
        #pragma unroll
        for (int ms = 0; ms < 2; ++ms)
            a3[ms] = *(const half8*)&s_act[act_idx64(4 * s + lhi, r0 + 16 * ms + llo, 0)];
        const int bbase = ((4 * s + lhi) * 128 + llo) << 3;
        #pragma unroll
        for (int t = 0; t < 8; ++t) {
            const half8 b = *(const half8*)(pw3 + bbase + (t << 7));
            acc3[0][t] = __builtin_amdgcn_mfma_f32_16x16x32_f16(a3[0], b, acc3[0][t], 0, 0, 0);
            acc3[1][t] = __builtin_amdgcn_mfma_f32_16x16x32_f16(a3[1], b, acc3[1][t], 0, 0, 0);
        }
    }

    float mb3v[8];
    #pragma unroll
    for (int t = 0; t < 8; ++t) mb3v[t] = mb3[16 * t + llo];

    #pragma unroll
    for (int ms = 0; ms < 2; ++ms)
        #pragma unroll
        for (int i = 0; i < 4; ++i) {
            const int row = r0 + 16 * ms + 4 * lhi + i;
            if (ATOMIC) {
                const size_t dbase = (size_t)s_dst[row] * 128;
                #pragma unroll
                for (int t = 0; t < 8; ++t)
                    unsafeAtomicAdd(&agg[dbase + 16 * t + llo], acc3[ms][t][i] + mb3v[t]);
            } else {
                _Float16* mrow = msgs + (size_t)(e0 + row) * 128;
                #pragma unroll
                for (int t = 0; t < 8; ++t)
                    __builtin_nontemporal_store((_Float16)(acc3[ms][t][i] + mb3v[t]), mrow + 16 * t + llo);
            }
        }
}

// ---------------- Update MLP + residual + LayerNorm ----------------
// FUSED=1: aggregate directly from dst-sorted msgs via offs (per-lane sums of
// the node's contiguous rows) — no agg/cnt buffers. FUSED=0: read agg+cnt.
template<int FUSED>
__global__ __launch_bounds__(256) void upd_kernel(
    const float* __restrict__ h, const _Float16* __restrict__ hf16,
    const _Float16* __restrict__ msgs, const int* __restrict__ offs,
    const _Float16* __restrict__ pu1, const _Float16* __restrict__ pu2,
    const float* __restrict__ ub1, const float* __restrict__ ub2,
    const float* __restrict__ gamma, const float* __restrict__ beta,
    const float* __restrict__ agg, const float* __restrict__ cnt,
    float* __restrict__ out)
{
    __shared__ __align__(16) _Float16 s_act[16 * 128 * 8];

    const int tid = threadIdx.x;
    const int n0  = blockIdx.x * 128;
    const int w = tid >> 6, l = tid & 63, lhi = l >> 4, llo = l & 15;
    const int r0 = 32 * w;
    const float4v fzero = {0.0f, 0.0f, 0.0f, 0.0f};

    float rcp[2];
    size_t nodeOff[2];
    int beg[2], end[2];
    #pragma unroll
    for (int ms = 0; ms < 2; ++ms) {
        int node = n0 + r0 + 16 * ms + llo;
        if (node >= NN) node = NN - 1;
        nodeOff[ms] = (size_t)node * 128;
        if (FUSED) {
            beg[ms] = offs[node]; end[ms] = offs[node + 1];
            rcp[ms] = 1.0f / ((float)(end[ms] - beg[ms]) + 1e-8f);
        } else {
            rcp[ms] = 1.0f / (cnt[node] + 1e-8f);
        }
    }

    // FUSED: per-lane aggregation of this node's message rows into 4 A-frags.
    half8 afA[2][4];
    if (FUSED) {
        #pragma unroll
        for (int ms = 0; ms < 2; ++ms) {
            float msum[4][8];
            #pragma unroll
            for (int s = 0; s < 4; ++s)
                #pragma unroll
                for (int j = 0; j < 8; ++j) msum[s][j] = 0.0f;
            for (int r = beg[ms]; r < end[ms]; ++r) {
                const half8* rp = (const half8*)(msgs + (size_t)r * 128) + lhi;
                #pragma unroll
                for (int s = 0; s < 4; ++s) {
                    half8 v = __builtin_nontemporal_load(rp + 4 * s);
                    #pragma unroll
                    for (int j = 0; j < 8; ++j) msum[s][j] += (float)v[j];
                }
            }
            #pragma unroll
            for (int s = 0; s < 4; ++s) {
                half8 a;
                #pragma unroll
                for (int j = 0; j < 8; ++j) a[j] = (_Float16)(msum[s][j] * rcp[ms]);
                afA[ms][s] = a;
            }
        }
    }

    // ---- GEMM U1: [hf16 | agg_mean] @ uW1, s=0..7 ----
    float4v acc[2][8];
    #pragma unroll
    for (int ms = 0; ms < 2; ++ms)
        #pragma unroll
        for (int t = 0; t < 8; ++t) acc[ms][t] = fzero;

    #pragma unroll
    for (int s = 0; s < 8; ++s) {
        half8 af[2];
        #pragma unroll
        for (int ms = 0; ms < 2; ++ms) {
            if (s < 4) {
                af[ms] = *(const half8*)(hf16 + nodeOff[ms] + 32 * s + 8 * lhi);
            } else if (FUSED) {
                af[ms] = afA[ms][s - 4];
            } else {
                const float* p = agg + nodeOff[ms] + 32 * (s - 4) + 8 * lhi;
                float4v x0 = *(const float4v*)p;
                float4v x1 = *(const float4v*)(p + 4);
                x0 *= rcp[ms]; x1 *= rcp[ms];
                af[ms] = cvt8(x0, x1);
            }
        }
        const int bbase = ((4 * s + lhi) * 128 + llo) << 3;
        #pragma unroll
        for (int t = 0; t < 8; ++t) {
            const half8 b = *(const half8*)(pu1 + bbase + (t << 7));
            acc[0][t] = __builtin_amdgcn_mfma_f32_16x16x32_f16(af[0], b, acc[0][t], 0, 0, 0);
            acc[1][t] = __builtin_amdgcn_mfma_f32_16x16x32_f16(af[1], b, acc[1][t], 0, 0, 0);
        }
    }

    #pragma unroll
    for (int t = 0; t < 8; ++t) {
        const int col = 16 * t + llo;
        const float b1 = ub1[col];
        #pragma unroll
        for (int ms = 0; ms < 2; ++ms)
            #pragma unroll
            for (int i = 0; i < 4; ++i) {
                const int row = r0 + 16 * ms + 4 * lhi + i;
                float v = gelu_tanh(acc[ms][t][i] + b1);
                s_act[act_idx(col >> 3, row, col & 7)] = (_Float16)v;
            }
    }

    float4v acc2[2][8];
    #pragma unroll
    for (int ms = 0; ms < 2; ++ms)
        #pragma unroll
        for (int t = 0; t < 8; ++t) acc2[ms][t] = fzero;

    #pragma unroll
    for (int s = 0; s < 4; ++s) {
        half8 af[2];
        #pragma unroll
        for (int ms = 0; ms < 2; ++ms)
            af[ms] = *(const half8*)&s_act[act_idx(4 * s + lhi, r0 + 16 * ms + llo, 0)];
        const int bbase = ((4 * s + lhi) * 128 + llo) << 3;
        #pragma unroll
        for (int t = 0; t < 8; ++t) {
            const half8 b = *(const half8*)(pu2 + bbase + (t << 7));
            acc2[0][t] = __builtin_amdgcn_mfma_f32_16x16x32_f16(af[0], b, acc2[0][t], 0, 0, 0);
            acc2[1][t] = __builtin_amdgcn_mfma_f32_16x16x32_f16(af[1], b, acc2[1][t], 0, 0, 0);
        }
    }

    float ub2v[8], gv[8], bv[8];
    #pragma unroll
    for (int t = 0; t < 8; ++t) {
        const int col = 16 * t + llo;
        ub2v[t] = ub2[col]; gv[t] = gamma[col]; bv[t] = beta[col];
    }

    #pragma unroll
    for (int ms = 0; ms < 2; ++ms)
        #pragma unroll
        for (int i = 0; i < 4; ++i) {
            const int noderow = n0 + r0 + 16 * ms + 4 * lhi + i;
            const int nodec = noderow < NN ? noderow : NN - 1;
            float y[8];
            float sum = 0.0f;
            #pragma unroll
            for (int t = 0; t < 8; ++t) {
                const int col = 16 * t + llo;
                float v = acc2[ms][t][i] + ub2v[t] + h[(size_t)nodec * 128 + col];
                y[t] = v; sum += v;
            }
            sum += __shfl_xor(sum, 1, 16);
            sum += __shfl_xor(sum, 2, 16);
            sum += __shfl_xor(sum, 4, 16);
            sum += __shfl_xor(sum, 8, 16);
            const float mu = sum * (1.0f / 128.0f);
            float sq = 0.0f;
            #pragma unroll
            for (int t = 0; t < 8; ++t) { float d = y[t] - mu; sq += d * d; }
            sq += __shfl_xor(sq, 1, 16);
            sq += __shfl_xor(sq, 2, 16);
            sq += __shfl_xor(sq, 4, 16);
            sq += __shfl_xor(sq, 8, 16);
            const float rs = rsqrtf(sq * (1.0f / 128.0f) + 1e-5f);
            if (noderow < NN) {
                #pragma unroll
                for (int t = 0; t < 8; ++t) {
                    const int col = 16 * t + llo;
                    out[(size_t)noderow * 128 + col] = (y[t] - mu) * rs * gv[t] + bv[t];
                }
            }
        }
}

extern "C" void kernel_launch(void* const* d_in, const int* in_sizes, int n_in,
                              void* d_out, int out_size, void* d_ws, size_t ws_size,
                              hipStream_t stream) {
    const float* h     = (const float*)d_in[0];
    const int*   ei    = (const int*)d_in[1];
    const float* eattr = (const float*)d_in[2];
    const float* mW1   = (const float*)d_in[3];
    const float* mb1   = (const float*)d_in[4];
    const float* mW2   = (const float*)d_in[5];
    const float* mb2   = (const float*)d_in[6];
    const float* mW3   = (const float*)d_in[7];
    const float* mb3   = (const float*)d_in[8];
    const float* uW1   = (const float*)d_in[9];
    const float* ub1   = (const float*)d_in[10];
    const float* uW2   = (const float*)d_in[11];
    const float* ub2   = (const float*)d_in[12];
    const float* gamma = (const float*)d_in[13];
    const float* beta  = (const float*)d_in[14];
    float* out = (float*)d_out;

    char* ws = (char*)d_ws;

    // Main layout (bytes)
    const size_t OFF_MSGS = 0;              // f16 600000*128*2 = 153,600,000
    const size_t OFF_HF   = 153600000;      // f16 12,800,000
    const size_t OFF_CNTI = 166400000;      // 200,000
    const size_t OFF_CURS = 166600000;      // 200,000
    const size_t OFF_OFFS = 166800000;      // 200,004 (padded)
    const size_t OFF_PERM = 167000064;      // 2,400,000
    const size_t OFF_PW   = 169400064;      // 245,760
    const size_t NEED     = 169645824;

    if (ws_size >= NEED) {
        _Float16* msgs  = (_Float16*)(ws + OFF_MSGS);
        _Float16* hf16  = (_Float16*)(ws + OFF_HF);
        int* cnt_i      = (int*)(ws + OFF_CNTI);
        int* cursor     = (int*)(ws + OFF_CURS);
        int* offs       = (int*)(ws + OFF_OFFS);
        int* perm       = (int*)(ws + OFF_PERM);
        _Float16* pw    = (_Float16*)(ws + OFF_PW);
        _Float16* pw1 = pw;
        _Float16* pw2 = pw + 40960;
        _Float16* pw3 = pw + 57344;
        _Float16* pu1 = pw + 73728;
        _Float16* pu2 = pw + 106496;

        hipMemsetAsync(ws + OFF_CNTI, 0, 400000, stream);   // cnt_i + cursor

        count_kernel<<<(E_TOTAL + 255) / 256, 256, 0, stream>>>(ei, cnt_i);
        scan_kernel<<<1, 1024, 0, stream>>>(cnt_i, offs);
        fill_kernel<<<(E_TOTAL + 255) / 256, 256, 0, stream>>>(ei, offs, cursor, perm);
        prep_kernel<<<1024, 256, 0, stream>>>(mW1, mW2, mW3, uW1, uW2, h, pw, hf16);

        msg_kernel<0><<<E_TOTAL / 64, 128, 0, stream>>>(
            hf16, ei, eattr, perm, pw1, pw2, pw3, mb1, mb2, mb3, msgs, nullptr, nullptr);

        upd_kernel<1><<<(NN + 127) / 128, 256, 0, stream>>>(
            h, hf16, msgs, offs, pu1, pu2, ub1, ub2, gamma, beta, nullptr, nullptr, out);
    } else {
        // Fallback: atomic-scatter path (~42 MB), sorted order for locality.
        float* agg     = (float*)ws;                       // 25,600,000
        float* cnt     = (float*)(ws + 25600000);          // 200,000
        _Float16* hf16 = (_Float16*)(ws + 25800000);       // 12,800,000
        int* cnt_i     = (int*)(ws + 38600000);            // 200,000
        int* cursor    = (int*)(ws + 38800000);            // 200,000
        int* offs      = (int*)(ws + 39000000);            // 200,004 (padded)
        int* perm      = (int*)(ws + 39200064);            // 2,400,000
        _Float16* pw   = (_Float16*)(ws + 41600064);       // 245,760
        _Float16* pw1 = pw;
        _Float16* pw2 = pw + 40960;
        _Float16* pw3 = pw + 57344;
        _Float16* pu1 = pw + 73728;
        _Float16* pu2 = pw + 106496;

        hipMemsetAsync(ws, 0, 25800000, stream);           // agg + cnt
        hipMemsetAsync(ws + 38600000, 0, 400000, stream);  // cnt_i + cursor

        count_kernel<<<(E_TOTAL + 255) / 256, 256, 0, stream>>>(ei, cnt_i);
        scan_kernel<<<1, 1024, 0, stream>>>(cnt_i, offs);
        fill_kernel<<<(E_TOTAL + 255) / 256, 256, 0, stream>>>(ei, offs, cursor, perm);
        prep_kernel<<<1024, 256, 0, stream>>>(mW1, mW2, mW3, uW1, uW2, h, pw, hf16);

        msg_kernel<1><<<E_TOTAL / 64, 128, 0, stream>>>(
            hf16, ei, eattr, perm, pw1, pw2, pw3, mb1, mb2, mb3, nullptr, agg, cnt);

        upd_kernel<0><<<(NN + 127) / 128, 256, 0, stream>>>(
            h, hf16, nullptr, nullptr, pu1, pu2, ub1, ub2, gamma, beta, agg, cnt, out);
    }
}

// Round 10
// 690.243 us; speedup vs baseline: 1.5739x; 1.0381x over previous
//
#include <hip/hip_runtime.h>

#define E_TOTAL 600000
#define NN 50000

typedef _Float16 half8 __attribute__((ext_vector_type(8)));
typedef _Float16 half2v __attribute__((ext_vector_type(2)));
typedef float float4v __attribute__((ext_vector_type(4)));
typedef float float2v __attribute__((ext_vector_type(2)));

// gelu(x) = x - x*rcp(exp(z)+1), z = x*(A + B*x^2). v_rcp_f32 ~1e-7 rel err.
// Verified R9: VALUBusy 41.5->23.5%, absmax unchanged.
__device__ __forceinline__ float gelu_tanh(float x) {
    const float A = 1.5957691216057308f;
    const float B = 0.0713548163f;
    float z = x * __builtin_fmaf(B, x * x, A);
    float ex = __expf(z);
    float r = __builtin_amdgcn_rcpf(ex + 1.0f);
    return __builtin_fmaf(-x, r, x);
}

// 128-row activation LDS swizzle (upd). Verified 0 conflicts R3/R5/R7/R8/R9.
__device__ __forceinline__ int act_idx(int c, int row, int q) {
    int idx = ((c * 128 + row) << 3) + q;
    idx ^= ((row >> 3) & 3) << 4;
    idx ^= (c & 1) << 3;
    return idx;
}
// 64-row variant (msg, 2-wave blocks).
__device__ __forceinline__ int act_idx64(int c, int row, int q) {
    int idx = ((c * 64 + row) << 3) + q;
    idx ^= ((row >> 3) & 3) << 4;
    idx ^= (c & 1) << 3;
    return idx;
}

__device__ __forceinline__ half8 cvt8(float4v x0, float4v x1) {
    half8 a;
    a[0] = (_Float16)x0[0]; a[1] = (_Float16)x0[1]; a[2] = (_Float16)x0[2]; a[3] = (_Float16)x0[3];
    a[4] = (_Float16)x1[0]; a[5] = (_Float16)x1[1]; a[6] = (_Float16)x1[2]; a[7] = (_Float16)x1[3];
    return a;
}

// Merged prep: pack 5 weight mats into MFMA B-fragment f16 order (122880)
// + convert h f32->f16 (800000 8-elem chunks).
__global__ __launch_bounds__(256) void prep_kernel(
    const float* __restrict__ mW1, const float* __restrict__ mW2, const float* __restrict__ mW3,
    const float* __restrict__ uW1, const float* __restrict__ uW2,
    const float* __restrict__ h,
    _Float16* __restrict__ pw, _Float16* __restrict__ hf)
{
    const int stride = gridDim.x * 256;
    for (int t = blockIdx.x * 256 + threadIdx.x; t < 922880; t += stride) {
        if (t < 122880) {
            const float* src;
            int loc;
            if (t < 40960)        { src = mW1; loc = t; }
            else if (t < 57344)   { src = mW2; loc = t - 40960; }
            else if (t < 73728)   { src = mW3; loc = t - 57344; }
            else if (t < 106496)  { src = uW1; loc = t - 73728; }
            else                  { src = uW2; loc = t - 106496; }
            int i   = loc & 7;
            int col = (loc >> 3) & 127;
            int c   = loc >> 10;
            pw[t] = (_Float16)src[(8 * c + i) * 128 + col];
        } else {
            int i = t - 122880;
            float4v a = ((const float4v*)h)[2 * i];
            float4v b = ((const float4v*)h)[2 * i + 1];
            ((half8*)hf)[i] = cvt8(a, b);
        }
    }
}

// edge_index dtype probe: int64 viewed as int32 has all-zero odd words.
__device__ __forceinline__ int detect_i64(const int* ei) {
    int allz = 1;
    #pragma unroll
    for (int j = 1; j < 64; j += 2) allz &= (ei[j] == 0);
    return allz;
}

// ---------------- CSR build (offs + inverse permutation rank) ----------------
__global__ __launch_bounds__(256) void count_kernel(const int* __restrict__ ei, int* __restrict__ cnt_i) {
    __shared__ int s_mode;
    if (threadIdx.x == 0) s_mode = detect_i64(ei);
    __syncthreads();
    int e = blockIdx.x * 256 + threadIdx.x;
    if (e >= E_TOTAL) return;
    int d = s_mode ? (int)((const long long*)ei)[E_TOTAL + e] : ei[E_TOTAL + e];
    atomicAdd(&cnt_i[d], 1);
}

__global__ __launch_bounds__(1024) void scan_kernel(const int* __restrict__ cnt_i, int* __restrict__ offs) {
    __shared__ int part[1024];
    const int t = threadIdx.x;
    const int PER = (NN + 1023) / 1024;   // 49
    const int base = t * PER;
    int s = 0;
    for (int j = 0; j < PER; ++j) { int idx = base + j; if (idx < NN) s += cnt_i[idx]; }
    part[t] = s;
    __syncthreads();
    for (int off = 1; off < 1024; off <<= 1) {
        int v = (t >= off) ? part[t - off] : 0;
        __syncthreads();
        part[t] += v;
        __syncthreads();
    }
    int run = (t == 0) ? 0 : part[t - 1];
    for (int j = 0; j < PER; ++j) { int idx = base + j; if (idx < NN) { offs[idx] = run; run += cnt_i[idx]; } }
    if (t == 1023) offs[NN] = part[1023];
}

// rank[e] = sorted slot of edge e (dst-major order).
__global__ __launch_bounds__(256) void fill_kernel(const int* __restrict__ ei, const int* __restrict__ offs,
                                                   int* __restrict__ cursor, int* __restrict__ rank) {
    __shared__ int s_mode;
    if (threadIdx.x == 0) s_mode = detect_i64(ei);
    __syncthreads();
    int e = blockIdx.x * 256 + threadIdx.x;
    if (e >= E_TOTAL) return;
    int d = s_mode ? (int)((const long long*)ei)[E_TOTAL + e] : ei[E_TOTAL + e];
    int pos = offs[d] + atomicAdd(&cursor[d], 1);
    rank[e] = pos;
}

// ---------------- aggregation: sequential stream, mean applied, f16 out ----------------
// msgs rows [offs[node], offs[node+1]) are contiguous. One wave per node.
// Output aggf[node][128] f16 = mean message, directly A-fragment loadable.
__global__ __launch_bounds__(256) void agg_kernel(const _Float16* __restrict__ msgs,
                                                  const int* __restrict__ offs,
                                                  _Float16* __restrict__ aggf) {
    const int node = blockIdx.x * 4 + (threadIdx.x >> 6);   // NN % 4 == 0
    const int l = threadIdx.x & 63;
    const int beg = offs[node], end = offs[node + 1];
    float2v s = {0.0f, 0.0f};
    const half2v* p = (const half2v*)msgs + (size_t)beg * 64 + l;
    int j = beg;
    for (; j + 3 < end; j += 4, p += 256) {
        half2v a = __builtin_nontemporal_load(p);
        half2v b = __builtin_nontemporal_load(p + 64);
        half2v c = __builtin_nontemporal_load(p + 128);
        half2v d = __builtin_nontemporal_load(p + 192);
        s.x += (float)a[0] + (float)b[0] + (float)c[0] + (float)d[0];
        s.y += (float)a[1] + (float)b[1] + (float)c[1] + (float)d[1];
    }
    for (; j < end; ++j, p += 64) {
        half2v v = __builtin_nontemporal_load(p);
        s.x += (float)v[0]; s.y += (float)v[1];
    }
    const float rcp = 1.0f / ((float)(end - beg) + 1e-8f);
    half2v o; o[0] = (_Float16)(s.x * rcp); o[1] = (_Float16)(s.y * rcp);
    ((half2v*)aggf)[(size_t)node * 64 + l] = o;
}

// ---------------- Message MLP (NATURAL edge order) ----------------
// 128 threads = 2 waves; 64 edges/block (600000/64 = 9375 exact).
// eattr is read SEQUENTIALLY (biggest stream now streaming, not gathered);
// h[src]/h[dst] gathered from 12.8MB hf16 (L2/L3-resident), 4-deep rotation.
// Output row = rank[e] (dst-sorted slot) via fire-and-forget NT store.
// ATOMIC=1 fallback: f32-atomic scatter into agg + cnt staging atomic.
template<int ATOMIC>
__global__ __launch_bounds__(128, 3) void msg_kernel(
    const _Float16* __restrict__ hf16, const int* __restrict__ ei, const float* __restrict__ eattr,
    const int* __restrict__ rank,
    const _Float16* __restrict__ pw1, const _Float16* __restrict__ pw2, const _Float16* __restrict__ pw3,
    const float* __restrict__ mb1, const float* __restrict__ mb2, const float* __restrict__ mb3,
    _Float16* __restrict__ msgs, float* __restrict__ agg, float* __restrict__ cnt)
{
    __shared__ int s_src[64];
    __shared__ int s_dst[64];
    __shared__ int s_rk[64];
    __shared__ int s_mode;
    __shared__ __align__(16) _Float16 s_act[16 * 64 * 8];   // 16 KB

    const int tid = threadIdx.x;
    const int e0  = blockIdx.x * 64;

    if (tid == 0) s_mode = detect_i64(ei);
    __syncthreads();

    if (tid < 64) {
        int e = e0 + tid;
        int srcn, dstn;
        if (s_mode) {
            const long long* e64 = (const long long*)ei;
            srcn = (int)e64[e];
            dstn = (int)e64[E_TOTAL + e];
        } else {
            srcn = ei[e];
            dstn = ei[E_TOTAL + e];
        }
        s_src[tid] = srcn;
        s_dst[tid] = dstn;
        if (ATOMIC) {
            unsafeAtomicAdd(&cnt[dstn], 1.0f);
        } else {
            s_rk[tid] = rank[e];
        }
    }
    __syncthreads();

    const int w = tid >> 6, l = tid & 63, lhi = l >> 4, llo = l & 15;
    const int r0 = 32 * w;
    const float4v fzero = {0.0f, 0.0f, 0.0f, 0.0f};

    const _Float16* srcP[2];
    const _Float16* dstP[2];
    const float*    eP[2];
    #pragma unroll
    for (int ms = 0; ms < 2; ++ms) {
        const int row = r0 + 16 * ms + llo;
        srcP[ms] = hf16 + (size_t)s_src[row] * 128 + 8 * lhi;
        dstP[ms] = hf16 + (size_t)s_dst[row] * 128 + 8 * lhi;
        eP[ms]   = eattr + (size_t)(e0 + row) * 64 + 8 * lhi;   // sequential stream
    }

    // ---- GEMM1: X[64][320] @ W1 (s=0..9), 4-deep A prefetch ----
    float4v acc[2][8];
    #pragma unroll
    for (int ms = 0; ms < 2; ++ms)
        #pragma unroll
        for (int t = 0; t < 8; ++t) acc[ms][t] = fzero;

    half8 af[4][2];
    #pragma unroll
    for (int s = 0; s < 4; ++s)
        #pragma unroll
        for (int ms = 0; ms < 2; ++ms)
            af[s][ms] = *(const half8*)(srcP[ms] + 32 * s);

    #pragma unroll
    for (int s = 0; s < 10; ++s) {
        const int bbase = ((4 * s + lhi) * 128 + llo) << 3;
        #pragma unroll
        for (int t = 0; t < 8; ++t) {
            const half8 b = *(const half8*)(pw1 + bbase + (t << 7));
            acc[0][t] = __builtin_amdgcn_mfma_f32_16x16x32_f16(af[s & 3][0], b, acc[0][t], 0, 0, 0);
            acc[1][t] = __builtin_amdgcn_mfma_f32_16x16x32_f16(af[s & 3][1], b, acc[1][t], 0, 0, 0);
        }
        if (s + 4 <= 9) {
            const int sn = s + 4;
            #pragma unroll
            for (int ms = 0; ms < 2; ++ms) {
                if (sn < 8) {
                    af[sn & 3][ms] = *(const half8*)(dstP[ms] + 32 * (sn - 4));
                } else {
                    const float* p = eP[ms] + 32 * (sn - 8);
                    float4v x0 = *(const float4v*)p;
                    float4v x1 = *(const float4v*)(p + 4);
                    af[sn & 3][ms] = cvt8(x0, x1);
                }
            }
        }
    }

    // E1: bias + gelu -> s_act
    #pragma unroll
    for (int t = 0; t < 8; ++t) {
        const int col = 16 * t + llo;
        const float b1 = mb1[col];
        #pragma unroll
        for (int ms = 0; ms < 2; ++ms)
            #pragma unroll
            for (int i = 0; i < 4; ++i) {
                const int row = r0 + 16 * ms + 4 * lhi + i;
                float v = gelu_tanh(acc[ms][t][i] + b1);
                s_act[act_idx64(col >> 3, row, col & 7)] = (_Float16)v;
            }
    }

    // ---- GEMM2 ----
    float4v acc2[2][8];
    #pragma unroll
    for (int ms = 0; ms < 2; ++ms)
        #pragma unroll
        for (int t = 0; t < 8; ++t) acc2[ms][t] = fzero;

    #pragma unroll
    for (int s = 0; s < 4; ++s) {
        half8 a2[2];
        #pragma unroll
        for (int ms = 0; ms < 2; ++ms)
            a2[ms] = *(const half8*)&s_act[act_idx64(4 * s + lhi, r0 + 16 * ms + llo, 0)];
        const int bbase = ((4 * s + lhi) * 128 + llo) << 3;
        #pragma unroll
        for (int t = 0; t < 8; ++t) {
            const half8 b = *(const half8*)(pw2 + bbase + (t << 7));
            acc2[0][t] = __builtin_amdgcn_mfma_f32_16x16x32_f16(a2[0], b, acc2[0][t], 0, 0, 0);
            acc2[1][t] = __builtin_amdgcn_mfma_f32_16x16x32_f16(a2[1], b, acc2[1][t], 0, 0, 0);
        }
    }

    #pragma unroll
    for (int t = 0; t < 8; ++t) {
        const int col = 16 * t + llo;
        const float b2 = mb2[col];
        #pragma unroll
        for (int ms = 0; ms < 2; ++ms)
            #pragma unroll
            for (int i = 0; i < 4; ++i) {
                const int row = r0 + 16 * ms + 4 * lhi + i;
                float v = gelu_tanh(acc2[ms][t][i] + b2);
                s_act[act_idx64(col >> 3, row, col & 7)] = (_Float16)v;
            }
    }

    // ---- GEMM3 ----
    float4v acc3[2][8];
    #pragma unroll
    for (int ms = 0; ms < 2; ++ms)
        #pragma unroll
        for (int t = 0; t < 8; ++t) acc3[ms][t] = fzero;

    #pragma unroll
    for (int s = 0; s < 4; ++s) {
        half8 a3[2];
        #pragma unroll
        for (int ms = 0; ms < 2; ++ms)
            a3[ms] = *(const half8*)&s_act[act_idx64(4 * s + lhi, r0 + 16 * ms + llo, 0)];
        const int bbase = ((4 * s + lhi) * 128 + llo) << 3;
        #pragma unroll
        for (int t = 0; t < 8; ++t) {
            const half8 b = *(const half8*)(pw3 + bbase + (t << 7));
            acc3[0][t] = __builtin_amdgcn_mfma_f32_16x16x32_f16(a3[0], b, acc3[0][t], 0, 0, 0);
            acc3[1][t] = __builtin_amdgcn_mfma_f32_16x16x32_f16(a3[1], b, acc3[1][t], 0, 0, 0);
        }
    }

    float mb3v[8];
    #pragma unroll
    for (int t = 0; t < 8; ++t) mb3v[t] = mb3[16 * t + llo];

    #pragma unroll
    for (int ms = 0; ms < 2; ++ms)
        #pragma unroll
        for (int i = 0; i < 4; ++i) {
            const int row = r0 + 16 * ms + 4 * lhi + i;
            if (ATOMIC) {
                const size_t dbase = (size_t)s_dst[row] * 128;
                #pragma unroll
                for (int t = 0; t < 8; ++t)
                    unsafeAtomicAdd(&agg[dbase + 16 * t + llo], acc3[ms][t][i] + mb3v[t]);
            } else {
                _Float16* mrow = msgs + (size_t)s_rk[row] * 128;   // sorted-slot scatter
                #pragma unroll
                for (int t = 0; t < 8; ++t)
                    __builtin_nontemporal_store((_Float16)(acc3[ms][t][i] + mb3v[t]), mrow + 16 * t + llo);
            }
        }
}

// ---------------- Update MLP + residual + LayerNorm ----------------
// AGGF16=1: agg mean precomputed as f16 [node][128] (direct A-frag loads).
// AGGF16=0: fallback — f32 agg + cnt, scale+cvt in-kernel.
template<int AGGF16>
__global__ __launch_bounds__(256) void upd_kernel(
    const float* __restrict__ h, const _Float16* __restrict__ hf16,
    const _Float16* __restrict__ aggf,
    const _Float16* __restrict__ pu1, const _Float16* __restrict__ pu2,
    const float* __restrict__ ub1, const float* __restrict__ ub2,
    const float* __restrict__ gamma, const float* __restrict__ beta,
    const float* __restrict__ agg, const float* __restrict__ cnt,
    float* __restrict__ out)
{
    __shared__ __align__(16) _Float16 s_act[16 * 128 * 8];

    const int tid = threadIdx.x;
    const int n0  = blockIdx.x * 128;
    const int w = tid >> 6, l = tid & 63, lhi = l >> 4, llo = l & 15;
    const int r0 = 32 * w;
    const float4v fzero = {0.0f, 0.0f, 0.0f, 0.0f};

    float rcp[2];
    size_t nodeOff[2];
    #pragma unroll
    for (int ms = 0; ms < 2; ++ms) {
        int node = n0 + r0 + 16 * ms + llo;
        if (node >= NN) node = NN - 1;
        nodeOff[ms] = (size_t)node * 128;
        if (!AGGF16) rcp[ms] = 1.0f / (cnt[node] + 1e-8f);
    }

    // ---- GEMM U1: [hf16 | agg_mean] @ uW1, s=0..7 ----
    float4v acc[2][8];
    #pragma unroll
    for (int ms = 0; ms < 2; ++ms)
        #pragma unroll
        for (int t = 0; t < 8; ++t) acc[ms][t] = fzero;

    #pragma unroll
    for (int s = 0; s < 8; ++s) {
        half8 af[2];
        #pragma unroll
        for (int ms = 0; ms < 2; ++ms) {
            if (s < 4) {
                af[ms] = *(const half8*)(hf16 + nodeOff[ms] + 32 * s + 8 * lhi);
            } else if (AGGF16) {
                af[ms] = *(const half8*)(aggf + nodeOff[ms] + 32 * (s - 4) + 8 * lhi);
            } else {
                const float* p = agg + nodeOff[ms] + 32 * (s - 4) + 8 * lhi;
                float4v x0 = *(const float4v*)p;
                float4v x1 = *(const float4v*)(p + 4);
                x0 *= rcp[ms]; x1 *= rcp[ms];
                af[ms] = cvt8(x0, x1);
            }
        }
        const int bbase = ((4 * s + lhi) * 128 + llo) << 3;
        #pragma unroll
        for (int t = 0; t < 8; ++t) {
            const half8 b = *(const half8*)(pu1 + bbase + (t << 7));
            acc[0][t] = __builtin_amdgcn_mfma_f32_16x16x32_f16(af[0], b, acc[0][t], 0, 0, 0);
            acc[1][t] = __builtin_amdgcn_mfma_f32_16x16x32_f16(af[1], b, acc[1][t], 0, 0, 0);
        }
    }

    #pragma unroll
    for (int t = 0; t < 8; ++t) {
        const int col = 16 * t + llo;
        const float b1 = ub1[col];
        #pragma unroll
        for (int ms = 0; ms < 2; ++ms)
            #pragma unroll
            for (int i = 0; i < 4; ++i) {
                const int row = r0 + 16 * ms + 4 * lhi + i;
                float v = gelu_tanh(acc[ms][t][i] + b1);
                s_act[act_idx(col >> 3, row, col & 7)] = (_Float16)v;
            }
    }

    float4v acc2[2][8];
    #pragma unroll
    for (int ms = 0; ms < 2; ++ms)
        #pragma unroll
        for (int t = 0; t < 8; ++t) acc2[ms][t] = fzero;

    #pragma unroll
    for (int s = 0; s < 4; ++s) {
        half8 af[2];
        #pragma unroll
        for (int ms = 0; ms < 2; ++ms)
            af[ms] = *(const half8*)&s_act[act_idx(4 * s + lhi, r0 + 16 * ms + llo, 0)];
        const int bbase = ((4 * s + lhi) * 128 + llo) << 3;
        #pragma unroll
        for (int t = 0; t < 8; ++t) {
            const half8 b = *(const half8*)(pu2 + bbase + (t << 7));
            acc2[0][t] = __builtin_amdgcn_mfma_f32_16x16x32_f16(af[0], b, acc2[0][t], 0, 0, 0);
            acc2[1][t] = __builtin_amdgcn_mfma_f32_16x16x32_f16(af[1], b, acc2[1][t], 0, 0, 0);
        }
    }

    float ub2v[8], gv[8], bv[8];
    #pragma unroll
    for (int t = 0; t < 8; ++t) {
        const int col = 16 * t + llo;
        ub2v[t] = ub2[col]; gv[t] = gamma[col]; bv[t] = beta[col];
    }

    #pragma unroll
    for (int ms = 0; ms < 2; ++ms)
        #pragma unroll
        for (int i = 0; i < 4; ++i) {
            const int noderow = n0 + r0 + 16 * ms + 4 * lhi + i;
            const int nodec = noderow < NN ? noderow : NN - 1;
            float y[8];
            float sum = 0.0f;
            #pragma unroll
            for (int t = 0; t < 8; ++t) {
                const int col = 16 * t + llo;
                float v = acc2[ms][t][i] + ub2v[t] + h[(size_t)nodec * 128 + col];
                y[t] = v; sum += v;
            }
            sum += __shfl_xor(sum, 1, 16);
            sum += __shfl_xor(sum, 2, 16);
            sum += __shfl_xor(sum, 4, 16);
            sum += __shfl_xor(sum, 8, 16);
            const float mu = sum * (1.0f / 128.0f);
            float sq = 0.0f;
            #pragma unroll
            for (int t = 0; t < 8; ++t) { float d = y[t] - mu; sq += d * d; }
            sq += __shfl_xor(sq, 1, 16);
            sq += __shfl_xor(sq, 2, 16);
            sq += __shfl_xor(sq, 4, 16);
            sq += __shfl_xor(sq, 8, 16);
            const float rs = rsqrtf(sq * (1.0f / 128.0f) + 1e-5f);
            if (noderow < NN) {
                #pragma unroll
                for (int t = 0; t < 8; ++t) {
                    const int col = 16 * t + llo;
                    out[(size_t)noderow * 128 + col] = (y[t] - mu) * rs * gv[t] + bv[t];
                }
            }
        }
}

extern "C" void kernel_launch(void* const* d_in, const int* in_sizes, int n_in,
                              void* d_out, int out_size, void* d_ws, size_t ws_size,
                              hipStream_t stream) {
    const float* h     = (const float*)d_in[0];
    const int*   ei    = (const int*)d_in[1];
    const float* eattr = (const float*)d_in[2];
    const float* mW1   = (const float*)d_in[3];
    const float* mb1   = (const float*)d_in[4];
    const float* mW2   = (const float*)d_in[5];
    const float* mb2   = (const float*)d_in[6];
    const float* mW3   = (const float*)d_in[7];
    const float* mb3   = (const float*)d_in[8];
    const float* uW1   = (const float*)d_in[9];
    const float* ub1   = (const float*)d_in[10];
    const float* uW2   = (const float*)d_in[11];
    const float* ub2   = (const float*)d_in[12];
    const float* gamma = (const float*)d_in[13];
    const float* beta  = (const float*)d_in[14];
    float* out = (float*)d_out;

    char* ws = (char*)d_ws;

    // Main layout (bytes)
    const size_t OFF_MSGS = 0;              // f16 600000*128*2 = 153,600,000
    const size_t OFF_HF   = 153600000;      // f16 12,800,000
    const size_t OFF_AGG  = 166400000;      // f16 12,800,000
    const size_t OFF_CNTI = 179200000;      // 200,000
    const size_t OFF_CURS = 179400000;      // 200,000
    const size_t OFF_OFFS = 179600000;      // 200,004 (padded to 200,064)
    const size_t OFF_RANK = 179800064;      // 2,400,000
    const size_t OFF_PW   = 182200064;      // 245,760
    const size_t NEED     = 182445824;

    if (ws_size >= NEED) {
        _Float16* msgs  = (_Float16*)(ws + OFF_MSGS);
        _Float16* hf16  = (_Float16*)(ws + OFF_HF);
        _Float16* aggf  = (_Float16*)(ws + OFF_AGG);
        int* cnt_i      = (int*)(ws + OFF_CNTI);
        int* cursor     = (int*)(ws + OFF_CURS);
        int* offs       = (int*)(ws + OFF_OFFS);
        int* rank       = (int*)(ws + OFF_RANK);
        _Float16* pw    = (_Float16*)(ws + OFF_PW);
        _Float16* pw1 = pw;
        _Float16* pw2 = pw + 40960;
        _Float16* pw3 = pw + 57344;
        _Float16* pu1 = pw + 73728;
        _Float16* pu2 = pw + 106496;

        hipMemsetAsync(ws + OFF_CNTI, 0, 400000, stream);   // cnt_i + cursor

        count_kernel<<<(E_TOTAL + 255) / 256, 256, 0, stream>>>(ei, cnt_i);
        scan_kernel<<<1, 1024, 0, stream>>>(cnt_i, offs);
        fill_kernel<<<(E_TOTAL + 255) / 256, 256, 0, stream>>>(ei, offs, cursor, rank);
        prep_kernel<<<1024, 256, 0, stream>>>(mW1, mW2, mW3, uW1, uW2, h, pw, hf16);

        msg_kernel<0><<<E_TOTAL / 64, 128, 0, stream>>>(
            hf16, ei, eattr, rank, pw1, pw2, pw3, mb1, mb2, mb3, msgs, nullptr, nullptr);

        agg_kernel<<<NN / 4, 256, 0, stream>>>(msgs, offs, aggf);

        upd_kernel<1><<<(NN + 127) / 128, 256, 0, stream>>>(
            h, hf16, aggf, pu1, pu2, ub1, ub2, gamma, beta, nullptr, nullptr, out);
    } else {
        // Fallback: atomic-scatter path (~39 MB), no CSR needed.
        float* agg     = (float*)ws;                       // 25,600,000
        float* cnt     = (float*)(ws + 25600000);          // 200,000
        _Float16* hf16 = (_Float16*)(ws + 25800000);       // 12,800,000
        _Float16* pw   = (_Float16*)(ws + 38600000);       // 245,760
        _Float16* pw1 = pw;
        _Float16* pw2 = pw + 40960;
        _Float16* pw3 = pw + 57344;
        _Float16* pu1 = pw + 73728;
        _Float16* pu2 = pw + 106496;

        hipMemsetAsync(ws, 0, 25800000, stream);           // agg + cnt

        prep_kernel<<<1024, 256, 0, stream>>>(mW1, mW2, mW3, uW1, uW2, h, pw, hf16);

        msg_kernel<1><<<E_TOTAL / 64, 128, 0, stream>>>(
            hf16, ei, eattr, nullptr, pw1, pw2, pw3, mb1, mb2, mb3, nullptr, agg, cnt);

        upd_kernel<0><<<(NN + 127) / 128, 256, 0, stream>>>(
            h, hf16, nullptr, pu1, pu2, ub1, ub2, gamma, beta, agg, cnt, out);
    }
}